// Round 8
// baseline (370.772 us; speedup 1.0000x reference)
//
#include <hip/hip_runtime.h>
#include <hip/hip_bf16.h>

#define BATCH 4
#define NPTS  8192
#define SPTS  2048
#define C1    128
#define C2    256
#define CIN   384   // C1+C2
#define H0    256
#define H1    128
#define NSLICE 32   // BN-stat accumulator slices
#define GRID_MLP 256

typedef __attribute__((ext_vector_type(8))) short bf16x8;
typedef __attribute__((ext_vector_type(4))) float f32x4;

__device__ __forceinline__ unsigned short f2bf(float x) {
  union { float f; unsigned u; } v; v.f = x;
  unsigned r = v.u + 0x7fff + ((v.u >> 16) & 1);   // RNE
  return (unsigned short)(r >> 16);
}
__device__ __forceinline__ float bf2f(unsigned short u) {
  union { unsigned u; float f; } v; v.u = ((unsigned)u) << 16; return v.f;
}

// Tree grid barrier: 32 padded arrival counters (max 8-deep RMW chain each, parallel
// lines) + block-0 release flag (read-only spin for everyone else). Counters are
// monotonic across barriers; prep zeroes the region each launch (graph-replay safe).
// bst layout (ints): [g*16] arrival counter for group g (g<32); [512] release flag.
__device__ __forceinline__ void grid_barrier(int* bst, int bid, int phase) {
  __syncthreads();
  if (threadIdx.x == 0) {
    __threadfence();
    __hip_atomic_fetch_add(&bst[(bid & 31) * 16], 1, __ATOMIC_RELEASE,
                           __HIP_MEMORY_SCOPE_AGENT);
    if (bid == 0) {
      int s;
      do {
        s = 0;
#pragma unroll
        for (int g = 0; g < 32; g++)
          s += __hip_atomic_load(&bst[g * 16], __ATOMIC_ACQUIRE, __HIP_MEMORY_SCOPE_AGENT);
        if (s < phase * GRID_MLP) __builtin_amdgcn_s_sleep(2);
      } while (s < phase * GRID_MLP);
      __hip_atomic_store(&bst[512], phase, __ATOMIC_RELEASE, __HIP_MEMORY_SCOPE_AGENT);
    } else {
      while (__hip_atomic_load(&bst[512], __ATOMIC_ACQUIRE, __HIP_MEMORY_SCOPE_AGENT) < phase)
        __builtin_amdgcn_s_sleep(2);
    }
  }
  __syncthreads();
}

// ---------------- fused prep: all input-only packing in one launch ----------------
__global__ __launch_bounds__(256) void prep_kernel(
    const float* __restrict__ p2, unsigned short* __restrict__ p2tb,
    const float* __restrict__ xyz2, float4* __restrict__ xp,
    const float* __restrict__ w0, const float* __restrict__ w1,
    unsigned short* __restrict__ Wp,
    const float* __restrict__ p1, unsigned short* __restrict__ Xp,
    float* __restrict__ stats) {
  __shared__ unsigned short shmem[64 * 136];
  int bid = blockIdx.x;
  int t = threadIdx.x;

  if (bid < 512) {  // ---- transpose p2 -> bf16 ----
    int b = bid >> 7, rem = bid & 127;
    int s0 = (rem >> 2) * 64, c0 = (rem & 3) * 64;
    const float* src = p2 + (size_t)b * C2 * SPTS;
    int ss = t & 63, cseg = t >> 6;
#pragma unroll
    for (int i = 0; i < 16; i++) {
      int cc = cseg + i * 4;
      shmem[ss * 72 + cc] = f2bf(src[(size_t)(c0 + cc) * SPTS + s0 + ss]);
    }
    __syncthreads();
    int s = t >> 2, chunk = t & 3;
    uint4 v0 = *(const uint4*)&shmem[s * 72 + chunk * 16];
    uint4 v1 = *(const uint4*)&shmem[s * 72 + chunk * 16 + 8];
    unsigned short* dst = p2tb + (size_t)b * SPTS * C2 + (size_t)(s0 + s) * C2 + c0 + chunk * 16;
    *(uint4*)dst = v0;
    *(uint4*)(dst + 8) = v1;
  } else if (bid < 1024) {  // ---- pack p1 ----
    int b2 = bid - 512;
    int b = b2 >> 7, n0 = (b2 & 127) * 64;
    int nn = t & 63, c4 = t >> 6;
#pragma unroll
    for (int i = 0; i < 32; i++) {
      int c = i * 4 + c4;
      shmem[nn * 136 + c] = f2bf(p1[((size_t)b * C1 + c) * NPTS + n0 + nn]);
    }
    __syncthreads();
    int n = t >> 2;
#pragma unroll
    for (int j = 0; j < 4; j++) {
      int ch = (t & 3) + j * 4;
      uint4 v = *(const uint4*)&shmem[n * 136 + ch * 8];
      *(uint4*)&Xp[((size_t)b * NPTS + n0 + n) * CIN + ch * 8] = v;
    }
  } else if (bid < 1056) {  // ---- prepack xyz2 (pre-negated, doubled) ----
    int idx = (bid - 1024) * 256 + t;
    int b = idx >> 11, s = idx & (SPTS - 1);
    const float* x2 = xyz2 + (size_t)b * 3 * SPTS;
    float x = x2[s], y = x2[SPTS + s], z = x2[2 * SPTS + s];
    xp[idx] = make_float4(-2.f * x, -2.f * y, -2.f * z, x * x + y * y + z * z);
  } else if (bid < 1184) {  // ---- pack weights ----
    int idx = ((bid - 1056) * 256 + t) * 4;
    const float* src = (idx < H0 * CIN) ? (w0 + idx) : (w1 + (idx - H0 * CIN));
    float4 v = *(const float4*)src;
    ushort4 o;
    o.x = f2bf(v.x); o.y = f2bf(v.y); o.z = f2bf(v.z); o.w = f2bf(v.w);
    *(ushort4*)(Wp + idx) = o;
  } else {  // ---- zero BN stat accumulators + barrier state (768 extra floats) ----
    int i4 = ((bid - 1184) * 256 + t) * 4;
    if (i4 < NSLICE * 768 + 768) *(float4*)(stats + i4) = make_float4(0.f, 0.f, 0.f, 0.f);
  }
}

// branchless top-3 insert: distances via fmin/fmed3, indices via cndmask (EXACT)
#define INS3(d, s, e0, e1, e2, j0, j1, j2)                        \
  {                                                               \
    bool lt0 = (d) < (e0), lt1 = (d) < (e1), lt2 = (d) < (e2);    \
    j2 = lt1 ? (j1) : (lt2 ? (s) : (j2));                         \
    j1 = lt0 ? (j0) : (lt1 ? (s) : (j1));                         \
    j0 = lt0 ? (s) : (j0);                                        \
    e2 = __builtin_amdgcn_fmed3f((d), (e1), (e2));                \
    e1 = __builtin_amdgcn_fmed3f((d), (e0), (e1));                \
    e0 = fminf((d), (e0));                                        \
  }

// ---------------- 3-NN search + fused interpolation ----------------
__global__ __launch_bounds__(1024) void knn_interp_kernel(
    const float* __restrict__ xyz1, const float4* __restrict__ xp,
    const unsigned short* __restrict__ p2tb, unsigned short* __restrict__ Xp) {
  int b = blockIdx.y;
  int t = threadIdx.x;
  int lane = t & 63;
  int w = __builtin_amdgcn_readfirstlane(t >> 6);  // 0..15
  int n = blockIdx.x * 64 + lane;
  const float* x1 = xyz1 + (size_t)b * 3 * NPTS;
  float px = x1[n], py = x1[NPTS + n], pz = x1[2 * NPTS + n];

  const int CHUNK = SPTS / 16;  // 128
  int sbase = w * CHUNK;
  const float4* cp = xp + (size_t)b * SPTS + sbase;

  float d0 = 3e38f, d1 = 3e38f, d2 = 3e38f;
  int i0 = 0, i1 = 0, i2 = 0;
#pragma unroll 8
  for (int j = 0; j < CHUNK; j++) {
    float4 c = cp[j];  // wave-uniform address -> scalar load
    float d = fmaf(c.z, pz, fmaf(c.y, py, fmaf(c.x, px, c.w)));
    int s = sbase + j;
    INS3(d, s, d0, d1, d2, i0, i1, i2);
  }

  __shared__ float dsh[16][64][3];
  __shared__ int   ish[16][64][3];
  __shared__ int   widx[64][3];
  __shared__ float wwgt[64][3];
  dsh[w][lane][0] = d0; dsh[w][lane][1] = d1; dsh[w][lane][2] = d2;
  ish[w][lane][0] = i0; ish[w][lane][1] = i1; ish[w][lane][2] = i2;
  __syncthreads();

  if (t < 256) {  // stage B: 4 groups merge 4 lists each
    int g = t >> 6, q = t & 63;
    float e0 = 3e38f, e1 = 3e38f, e2 = 3e38f;
    int j0 = 0, j1 = 0, j2 = 0;
#pragma unroll
    for (int c = 0; c < 4; c++) {
#pragma unroll
      for (int k = 0; k < 3; k++) {
        float d = dsh[4 * g + c][q][k];
        int s = ish[4 * g + c][q][k];
        INS3(d, s, e0, e1, e2, j0, j1, j2);
      }
    }
    dsh[4 * g][q][0] = e0; dsh[4 * g][q][1] = e1; dsh[4 * g][q][2] = e2;
    ish[4 * g][q][0] = j0; ish[4 * g][q][1] = j1; ish[4 * g][q][2] = j2;
  }
  __syncthreads();

  if (t < 64) {  // stage C: final merge; weights -> LDS
    float e0 = 3e38f, e1 = 3e38f, e2 = 3e38f;
    int j0 = 0, j1 = 0, j2 = 0;
#pragma unroll
    for (int c = 0; c < 4; c++) {
#pragma unroll
      for (int k = 0; k < 3; k++) {
        float d = dsh[4 * c][t][k];
        int s = ish[4 * c][t][k];
        INS3(d, s, e0, e1, e2, j0, j1, j2);
      }
    }
    float qq = fmaf(px, px, fmaf(py, py, pz * pz));
    float r0 = 1.f / (e0 + qq + 1e-8f);
    float r1 = 1.f / (e1 + qq + 1e-8f);
    float r2 = 1.f / (e2 + qq + 1e-8f);
    float rs = 1.f / (r0 + r1 + r2);
    widx[t][0] = j0; widx[t][1] = j1; widx[t][2] = j2;
    wwgt[t][0] = r0 * rs; wwgt[t][1] = r1 * rs; wwgt[t][2] = r2 * rs;
  }
  __syncthreads();

  // ---- fused interpolation ----
  const unsigned short* base = p2tb + (size_t)b * SPTS * C2;
  int c2 = (t & 127) * 2;
  int psub = t >> 7;
  unsigned short* xrow = Xp + ((size_t)b * NPTS + blockIdx.x * 64) * CIN + C1 + c2;
#pragma unroll
  for (int i = 0; i < 8; i++) {
    int pl = psub + i * 8;
    int g0 = widx[pl][0], g1 = widx[pl][1], g2 = widx[pl][2];
    float w0v = wwgt[pl][0], w1v = wwgt[pl][1], w2v = wwgt[pl][2];
    unsigned a0 = *(const unsigned*)(base + (size_t)g0 * C2 + c2);
    unsigned a1 = *(const unsigned*)(base + (size_t)g1 * C2 + c2);
    unsigned a2 = *(const unsigned*)(base + (size_t)g2 * C2 + c2);
    float v0 = w0v * bf2f((unsigned short)a0) + w1v * bf2f((unsigned short)a1) +
               w2v * bf2f((unsigned short)a2);
    float v1 = w0v * bf2f((unsigned short)(a0 >> 16)) + w1v * bf2f((unsigned short)(a1 >> 16)) +
               w2v * bf2f((unsigned short)(a2 >> 16));
    unsigned pk = (unsigned)f2bf(v0) | ((unsigned)f2bf(v1) << 16);
    *(unsigned*)(xrow + (size_t)pl * CIN) = pk;
  }
}

// ---------------- fused MLP: gemm0 -> gridbar -> BN0+ReLU+gemm1 -> gridbar -> BN1 ----
__global__ __launch_bounds__(256, 1) void fused_mlp_kernel(
    const unsigned short* __restrict__ Wp, const unsigned short* __restrict__ Xp,
    const float* __restrict__ bias0, const float* __restrict__ g0,
    const float* __restrict__ be0, const float* __restrict__ bias1,
    const float* __restrict__ g1, const float* __restrict__ be1,
    float* __restrict__ out, float* __restrict__ stats) {
  // LDS: 3 staging bufs (A 256x32 @0, B 128x32 @8192) = 36864 elems (72KB);
  // epilogue aliases it as ytile[128][264] (67.6KB).
  __shared__ unsigned short lds[36864];
  __shared__ float aS0[256], sS0[256], aS1[128], sS1[128];
  int* bst = (int*)(stats + NSLICE * 768);

  int bid = blockIdx.x;
  int b = bid >> 6;
  int n0 = (bid & 63) * 128;
  int t = threadIdx.x;
  int lane = t & 63;
  int w = __builtin_amdgcn_readfirstlane(t >> 6);  // 0..3
  int mi = lane & 15, kq = (lane >> 4) * 8;
  int rq = (lane >> 4) * 4;
  int rA = lane >> 2;
  int cofs = (lane & 3) * 8;
  int slice = bid & (NSLICE - 1);

  // ================= Phase 1: gemm0 (Wp0 256x384 @ Xp-tile 128x384) =================
  int mq = (w & 1) * 128;   // m-range 128 per wave (8 frags)
  int nh = (w >> 1) * 64;   // n-range 64 per wave (4 frags)
  const unsigned short* Xb = Xp + ((size_t)b * NPTS + n0) * CIN;

  auto stage = [&](int buf, int k0) {
    unsigned short* dstA = lds + buf * 12288;
    unsigned short* dstB = dstA + 8192;
#pragma unroll
    for (int q = 0; q < 4; q++) {          // A: 256 rows, 64/wave
      int r0 = w * 64 + q * 16;
      const unsigned short* ga = Wp + (size_t)(r0 + rA) * CIN + k0 + cofs;
      __builtin_amdgcn_global_load_lds(
          (const __attribute__((address_space(1))) void*)ga,
          (__attribute__((address_space(3))) void*)(dstA + r0 * 32), 16, 0, 0);
    }
#pragma unroll
    for (int q = 0; q < 2; q++) {          // B: 128 rows, 32/wave
      int r0 = w * 32 + q * 16;
      const unsigned short* gb = Xb + (size_t)(r0 + rA) * CIN + k0 + cofs;
      __builtin_amdgcn_global_load_lds(
          (const __attribute__((address_space(1))) void*)gb,
          (__attribute__((address_space(3))) void*)(dstB + r0 * 32), 16, 0, 0);
    }
  };

  constexpr int NT0 = CIN / 32;  // 12
  f32x4 acc[8][4] = {};

  stage(0, 0);
  stage(1, 32);

#pragma unroll
  for (int kt = 0; kt < NT0; ++kt) {
    if (kt < NT0 - 1) asm volatile("s_waitcnt vmcnt(6)" ::: "memory");
    else              asm volatile("s_waitcnt vmcnt(0)" ::: "memory");
    __builtin_amdgcn_s_barrier();
    asm volatile("" ::: "memory");
    __builtin_amdgcn_sched_barrier(0);

    if (kt + 2 < NT0) stage((kt + 2) % 3, (kt + 2) * 32);

    const unsigned short* Ac = lds + (kt % 3) * 12288;
    const unsigned short* Bc = Ac + 8192;
    bf16x8 af[8], bfr[4];
#pragma unroll
    for (int i = 0; i < 8; i++)
      af[i] = *(const bf16x8*)(Ac + (mq + i * 16 + mi) * 32 + kq);
#pragma unroll
    for (int j = 0; j < 4; j++)
      bfr[j] = *(const bf16x8*)(Bc + (nh + j * 16 + mi) * 32 + kq);
#pragma unroll
    for (int i = 0; i < 8; i++)
#pragma unroll
      for (int j = 0; j < 4; j++)
        acc[i][j] = __builtin_amdgcn_mfma_f32_16x16x32_bf16(
            af[i], bfr[j], acc[i][j], 0, 0, 0);
  }

  __syncthreads();  // staging LDS dead -> reuse as ytile[128][264]
  unsigned short* yt = lds;
  {
    float* sb = stats + slice * 768;        // sum0
    float* qb = sb + 256;                   // sq0
#pragma unroll
    for (int i = 0; i < 8; i++) {
#pragma unroll
      for (int rp = 0; rp < 2; rp++) {
        int m0 = mq + i * 16 + rq + rp * 2;
        float bva = bias0[m0], bvb = bias0[m0 + 1];
        float psA = 0.f, pqA = 0.f, psB = 0.f, pqB = 0.f;
#pragma unroll
        for (int j = 0; j < 4; j++) {
          int n = nh + j * 16 + mi;
          float va = acc[i][j][rp * 2] + bva;
          float vb = acc[i][j][rp * 2 + 1] + bvb;
          psA += va; pqA += va * va; psB += vb; pqB += vb * vb;
          *(unsigned*)&yt[n * 264 + m0] = (unsigned)f2bf(va) | ((unsigned)f2bf(vb) << 16);
        }
#pragma unroll
        for (int off = 1; off < 16; off <<= 1) {
          psA += __shfl_xor(psA, off, 16); pqA += __shfl_xor(pqA, off, 16);
          psB += __shfl_xor(psB, off, 16); pqB += __shfl_xor(pqB, off, 16);
        }
        if (mi == 0) {
          atomicAdd(&sb[m0], psA); atomicAdd(&qb[m0], pqA);
          atomicAdd(&sb[m0 + 1], psB); atomicAdd(&qb[m0 + 1], pqB);
        }
      }
    }
  }
  grid_barrier(bst, bid, 1);

  // ================= Phase 2: BN0 coeffs + apply (LDS) + gemm1 =================
  {
    float ms = 0.f, vs = 0.f;
#pragma unroll 4
    for (int sl = 0; sl < NSLICE; sl++) {
      ms += __hip_atomic_load(&stats[sl * 768 + t], __ATOMIC_RELAXED, __HIP_MEMORY_SCOPE_AGENT);
      vs += __hip_atomic_load(&stats[sl * 768 + 256 + t], __ATOMIC_RELAXED, __HIP_MEMORY_SCOPE_AGENT);
    }
    const float inv = 1.f / (float)(BATCH * NPTS);
    float mean = ms * inv;
    float var = vs * inv - mean * mean;
    float ia = g0[t] * rsqrtf(var + 1e-5f);
    aS0[t] = ia; sS0[t] = be0[t] - mean * ia;
  }
  __syncthreads();
  {
    int row = t >> 1, c0 = (t & 1) * 128;
#pragma unroll
    for (int jj = 0; jj < 16; jj++) {
      bf16x8 v = *(bf16x8*)&yt[row * 264 + c0 + jj * 8];
      bf16x8 o;
#pragma unroll
      for (int e = 0; e < 8; e++) {
        int ch = c0 + jj * 8 + e;
        float f = fmaxf(fmaf(bf2f((unsigned short)v[e]), aS0[ch], sS0[ch]), 0.f);
        o[e] = (short)f2bf(f);
      }
      *(bf16x8*)&yt[row * 264 + c0 + jj * 8] = o;
    }
  }
  __syncthreads();

  int mh1 = (w & 1) * 64, nh1 = (w >> 1) * 64;
  const unsigned short* W1 = Wp + H0 * CIN;  // 128x256, L2-resident
  f32x4 acc1[4][4] = {};
#pragma unroll
  for (int kt = 0; kt < H0 / 32; kt++) {     // 8
    bf16x8 a1[4], b1f[4];
#pragma unroll
    for (int i = 0; i < 4; i++)
      a1[i] = *(const bf16x8*)(W1 + (size_t)(mh1 + i * 16 + mi) * H0 + kt * 32 + kq);
#pragma unroll
    for (int j = 0; j < 4; j++)
      b1f[j] = *(const bf16x8*)&yt[(nh1 + j * 16 + mi) * 264 + kt * 32 + kq];
#pragma unroll
    for (int i = 0; i < 4; i++)
#pragma unroll
      for (int j = 0; j < 4; j++)
        acc1[i][j] = __builtin_amdgcn_mfma_f32_16x16x32_bf16(
            a1[i], b1f[j], acc1[i][j], 0, 0, 0);
  }

  {
    float* sb = stats + slice * 768 + 512;   // sum1
    float* qb = sb + 128;                    // sq1
#pragma unroll
    for (int i = 0; i < 4; i++) {
#pragma unroll
      for (int r = 0; r < 4; r++) {
        int m = mh1 + i * 16 + rq + r;
        float bv = bias1[m];
        float ps = 0.f, pq = 0.f;
#pragma unroll
        for (int j = 0; j < 4; j++) {
          float v = acc1[i][j][r] + bv;
          acc1[i][j][r] = v;
          ps += v; pq += v * v;
        }
#pragma unroll
        for (int off = 1; off < 16; off <<= 1) {
          ps += __shfl_xor(ps, off, 16);
          pq += __shfl_xor(pq, off, 16);
        }
        if (mi == 0) { atomicAdd(&sb[m], ps); atomicAdd(&qb[m], pq); }
      }
    }
  }
  grid_barrier(bst, bid, 2);

  // ================= Phase 3: BN1 coeffs + apply from registers + store =================
  if (t < 128) {
    float ms = 0.f, vs = 0.f;
#pragma unroll 4
    for (int sl = 0; sl < NSLICE; sl++) {
      ms += __hip_atomic_load(&stats[sl * 768 + 512 + t], __ATOMIC_RELAXED, __HIP_MEMORY_SCOPE_AGENT);
      vs += __hip_atomic_load(&stats[sl * 768 + 640 + t], __ATOMIC_RELAXED, __HIP_MEMORY_SCOPE_AGENT);
    }
    const float inv = 1.f / (float)(BATCH * NPTS);
    float mean = ms * inv;
    float var = vs * inv - mean * mean;
    float ia = g1[t] * rsqrtf(var + 1e-5f);
    aS1[t] = ia; sS1[t] = be1[t] - mean * ia;
  }
  __syncthreads();
  {
    float* Yo = out + (size_t)b * H1 * NPTS;
#pragma unroll
    for (int i = 0; i < 4; i++) {
#pragma unroll
      for (int r = 0; r < 4; r++) {
        int m = mh1 + i * 16 + rq + r;
        float ia = aS1[m], sh = sS1[m];
#pragma unroll
        for (int j = 0; j < 4; j++) {
          int n = n0 + nh1 + j * 16 + mi;
          Yo[(size_t)m * NPTS + n] = fmaxf(fmaf(acc1[i][j][r], ia, sh), 0.f);
        }
      }
    }
  }
}

extern "C" void kernel_launch(void* const* d_in, const int* in_sizes, int n_in,
                              void* d_out, int out_size, void* d_ws, size_t ws_size,
                              hipStream_t stream) {
  const float* xyz1    = (const float*)d_in[0];
  const float* xyz2    = (const float*)d_in[1];
  const float* points1 = (const float*)d_in[2];
  const float* points2 = (const float*)d_in[3];
  const float* w0      = (const float*)d_in[4];
  const float* b0      = (const float*)d_in[5];
  const float* gamma0  = (const float*)d_in[6];
  const float* beta0   = (const float*)d_in[7];
  const float* w1      = (const float*)d_in[8];
  const float* b1      = (const float*)d_in[9];
  const float* gamma1  = (const float*)d_in[10];
  const float* beta1   = (const float*)d_in[11];
  float* out = (float*)d_out;

  char* ws = (char*)d_ws;
  unsigned short* p2tb = (unsigned short*)ws;  ws += (size_t)BATCH * SPTS * C2 * 2;   // 4.2 MB
  unsigned short* Xp = (unsigned short*)ws;    ws += (size_t)BATCH * NPTS * CIN * 2;  // 25.2 MB
  unsigned short* Wp = (unsigned short*)ws;    ws += (size_t)(H0 * CIN + H1 * H0) * 2;
  float4* xyz2p = (float4*)(((uintptr_t)ws + 15) & ~(uintptr_t)15);
  ws = (char*)xyz2p + (size_t)BATCH * SPTS * 16;
  float* stats = (float*)ws;                   ws += (size_t)(NSLICE * 768 + 768) * 4;
  // per-slice layout: [0,256)=sum0, [256,512)=sq0, [512,640)=sum1, [640,768)=sq1;
  // stats[NSLICE*768 ..]: barrier state (32 padded counters + flag)
  (void)ws_size; (void)in_sizes; (void)n_in; (void)out_size;

  prep_kernel<<<dim3(1209), 256, 0, stream>>>(points2, p2tb, xyz2, xyz2p,
                                              w0, w1, Wp, points1, Xp, stats);
  knn_interp_kernel<<<dim3(NPTS / 64, BATCH), 1024, 0, stream>>>(xyz1, xyz2p, p2tb, Xp);
  fused_mlp_kernel<<<dim3(GRID_MLP), 256, 0, stream>>>(
      Wp, Xp, b0, gamma0, beta0, b1, gamma1, beta1, out, stats);
}

// Round 9
// 184.676 us; speedup vs baseline: 2.0077x; 2.0077x over previous
//
#include <hip/hip_runtime.h>
#include <hip/hip_bf16.h>

#define BATCH 4
#define NPTS  8192
#define SPTS  2048
#define C1    128
#define C2    256
#define CIN   384   // C1+C2
#define H0    256
#define H1    128
#define NSLICE 32   // BN-stat accumulator slices

typedef __attribute__((ext_vector_type(8))) short bf16x8;
typedef __attribute__((ext_vector_type(4))) float f32x4;

__device__ __forceinline__ unsigned short f2bf(float x) {
  union { float f; unsigned u; } v; v.f = x;
  unsigned r = v.u + 0x7fff + ((v.u >> 16) & 1);   // RNE
  return (unsigned short)(r >> 16);
}
__device__ __forceinline__ float bf2f(unsigned short u) {
  union { unsigned u; float f; } v; v.u = ((unsigned)u) << 16; return v.f;
}

// ---------------- fused prep: all input-only packing in one launch ----------------
__global__ __launch_bounds__(256) void prep_kernel(
    const float* __restrict__ p2, unsigned short* __restrict__ p2tb,
    const float* __restrict__ xyz2, float4* __restrict__ xp,
    const float* __restrict__ w0, const float* __restrict__ w1,
    unsigned short* __restrict__ Wp,
    const float* __restrict__ p1, unsigned short* __restrict__ Xp,
    float* __restrict__ stats) {
  __shared__ unsigned short shmem[64 * 136];
  int bid = blockIdx.x;
  int t = threadIdx.x;

  if (bid < 512) {  // ---- transpose p2 -> bf16 ----
    int b = bid >> 7, rem = bid & 127;
    int s0 = (rem >> 2) * 64, c0 = (rem & 3) * 64;
    const float* src = p2 + (size_t)b * C2 * SPTS;
    int ss = t & 63, cseg = t >> 6;
#pragma unroll
    for (int i = 0; i < 16; i++) {
      int cc = cseg + i * 4;
      shmem[ss * 72 + cc] = f2bf(src[(size_t)(c0 + cc) * SPTS + s0 + ss]);
    }
    __syncthreads();
    int s = t >> 2, chunk = t & 3;
    uint4 v0 = *(const uint4*)&shmem[s * 72 + chunk * 16];
    uint4 v1 = *(const uint4*)&shmem[s * 72 + chunk * 16 + 8];
    unsigned short* dst = p2tb + (size_t)b * SPTS * C2 + (size_t)(s0 + s) * C2 + c0 + chunk * 16;
    *(uint4*)dst = v0;
    *(uint4*)(dst + 8) = v1;
  } else if (bid < 1024) {  // ---- pack p1 ----
    int b2 = bid - 512;
    int b = b2 >> 7, n0 = (b2 & 127) * 64;
    int nn = t & 63, c4 = t >> 6;
#pragma unroll
    for (int i = 0; i < 32; i++) {
      int c = i * 4 + c4;
      shmem[nn * 136 + c] = f2bf(p1[((size_t)b * C1 + c) * NPTS + n0 + nn]);
    }
    __syncthreads();
    int n = t >> 2;
#pragma unroll
    for (int j = 0; j < 4; j++) {
      int ch = (t & 3) + j * 4;
      uint4 v = *(const uint4*)&shmem[n * 136 + ch * 8];
      *(uint4*)&Xp[((size_t)b * NPTS + n0 + n) * CIN + ch * 8] = v;
    }
  } else if (bid < 1056) {  // ---- prepack xyz2 (pre-negated, doubled) ----
    int idx = (bid - 1024) * 256 + t;
    int b = idx >> 11, s = idx & (SPTS - 1);
    const float* x2 = xyz2 + (size_t)b * 3 * SPTS;
    float x = x2[s], y = x2[SPTS + s], z = x2[2 * SPTS + s];
    xp[idx] = make_float4(-2.f * x, -2.f * y, -2.f * z, x * x + y * y + z * z);
  } else if (bid < 1184) {  // ---- pack weights ----
    int idx = ((bid - 1056) * 256 + t) * 4;
    const float* src = (idx < H0 * CIN) ? (w0 + idx) : (w1 + (idx - H0 * CIN));
    float4 v = *(const float4*)src;
    ushort4 o;
    o.x = f2bf(v.x); o.y = f2bf(v.y); o.z = f2bf(v.z); o.w = f2bf(v.w);
    *(ushort4*)(Wp + idx) = o;
  } else {  // ---- zero BN stat accumulators ----
    int i4 = ((bid - 1184) * 256 + t) * 4;
    if (i4 < NSLICE * 768) *(float4*)(stats + i4) = make_float4(0.f, 0.f, 0.f, 0.f);
  }
}

// branchless top-3 insert: distances via fmin/fmed3, indices via cndmask (EXACT)
#define INS3(d, s, e0, e1, e2, j0, j1, j2)                        \
  {                                                               \
    bool lt0 = (d) < (e0), lt1 = (d) < (e1), lt2 = (d) < (e2);    \
    j2 = lt1 ? (j1) : (lt2 ? (s) : (j2));                         \
    j1 = lt0 ? (j0) : (lt1 ? (s) : (j1));                         \
    j0 = lt0 ? (s) : (j0);                                        \
    e2 = __builtin_amdgcn_fmed3f((d), (e1), (e2));                \
    e1 = __builtin_amdgcn_fmed3f((d), (e0), (e1));                \
    e0 = fminf((d), (e0));                                        \
  }

// ---------------- 3-NN search + fused interpolation ----------------
__global__ __launch_bounds__(1024) void knn_interp_kernel(
    const float* __restrict__ xyz1, const float4* __restrict__ xp,
    const unsigned short* __restrict__ p2tb, unsigned short* __restrict__ Xp) {
  int b = blockIdx.y;
  int t = threadIdx.x;
  int lane = t & 63;
  int w = __builtin_amdgcn_readfirstlane(t >> 6);  // 0..15
  int n = blockIdx.x * 64 + lane;
  const float* x1 = xyz1 + (size_t)b * 3 * NPTS;
  float px = x1[n], py = x1[NPTS + n], pz = x1[2 * NPTS + n];

  const int CHUNK = SPTS / 16;  // 128
  int sbase = w * CHUNK;
  const float4* cp = xp + (size_t)b * SPTS + sbase;

  float d0 = 3e38f, d1 = 3e38f, d2 = 3e38f;
  int i0 = 0, i1 = 0, i2 = 0;
#pragma unroll 8
  for (int j = 0; j < CHUNK; j++) {
    float4 c = cp[j];  // wave-uniform address -> scalar load
    float d = fmaf(c.z, pz, fmaf(c.y, py, fmaf(c.x, px, c.w)));
    int s = sbase + j;
    INS3(d, s, d0, d1, d2, i0, i1, i2);
  }

  __shared__ float dsh[16][64][3];
  __shared__ int   ish[16][64][3];
  __shared__ int   widx[64][3];
  __shared__ float wwgt[64][3];
  dsh[w][lane][0] = d0; dsh[w][lane][1] = d1; dsh[w][lane][2] = d2;
  ish[w][lane][0] = i0; ish[w][lane][1] = i1; ish[w][lane][2] = i2;
  __syncthreads();

  if (t < 256) {  // stage B: 4 groups merge 4 lists each
    int g = t >> 6, q = t & 63;
    float e0 = 3e38f, e1 = 3e38f, e2 = 3e38f;
    int j0 = 0, j1 = 0, j2 = 0;
#pragma unroll
    for (int c = 0; c < 4; c++) {
#pragma unroll
      for (int k = 0; k < 3; k++) {
        float d = dsh[4 * g + c][q][k];
        int s = ish[4 * g + c][q][k];
        INS3(d, s, e0, e1, e2, j0, j1, j2);
      }
    }
    dsh[4 * g][q][0] = e0; dsh[4 * g][q][1] = e1; dsh[4 * g][q][2] = e2;
    ish[4 * g][q][0] = j0; ish[4 * g][q][1] = j1; ish[4 * g][q][2] = j2;
  }
  __syncthreads();

  if (t < 64) {  // stage C: final merge; weights -> LDS
    float e0 = 3e38f, e1 = 3e38f, e2 = 3e38f;
    int j0 = 0, j1 = 0, j2 = 0;
#pragma unroll
    for (int c = 0; c < 4; c++) {
#pragma unroll
      for (int k = 0; k < 3; k++) {
        float d = dsh[4 * c][t][k];
        int s = ish[4 * c][t][k];
        INS3(d, s, e0, e1, e2, j0, j1, j2);
      }
    }
    float qq = fmaf(px, px, fmaf(py, py, pz * pz));
    float r0 = 1.f / (e0 + qq + 1e-8f);
    float r1 = 1.f / (e1 + qq + 1e-8f);
    float r2 = 1.f / (e2 + qq + 1e-8f);
    float rs = 1.f / (r0 + r1 + r2);
    widx[t][0] = j0; widx[t][1] = j1; widx[t][2] = j2;
    wwgt[t][0] = r0 * rs; wwgt[t][1] = r1 * rs; wwgt[t][2] = r2 * rs;
  }
  __syncthreads();

  // ---- fused interpolation ----
  const unsigned short* base = p2tb + (size_t)b * SPTS * C2;
  int c2 = (t & 127) * 2;
  int psub = t >> 7;
  unsigned short* xrow = Xp + ((size_t)b * NPTS + blockIdx.x * 64) * CIN + C1 + c2;
#pragma unroll
  for (int i = 0; i < 8; i++) {
    int pl = psub + i * 8;
    int g0 = widx[pl][0], g1 = widx[pl][1], g2 = widx[pl][2];
    float w0v = wwgt[pl][0], w1v = wwgt[pl][1], w2v = wwgt[pl][2];
    unsigned a0 = *(const unsigned*)(base + (size_t)g0 * C2 + c2);
    unsigned a1 = *(const unsigned*)(base + (size_t)g1 * C2 + c2);
    unsigned a2 = *(const unsigned*)(base + (size_t)g2 * C2 + c2);
    float v0 = w0v * bf2f((unsigned short)a0) + w1v * bf2f((unsigned short)a1) +
               w2v * bf2f((unsigned short)a2);
    float v1 = w0v * bf2f((unsigned short)(a0 >> 16)) + w1v * bf2f((unsigned short)(a1 >> 16)) +
               w2v * bf2f((unsigned short)(a2 >> 16));
    unsigned pk = (unsigned)f2bf(v0) | ((unsigned)f2bf(v1) << 16);
    *(unsigned*)(xrow + (size_t)pl * CIN) = pk;
  }
}

// ---------------- GEMM0: full 256-m per block (Xp fetched ONCE), triple-buffered
// counted-vmcnt staging; epilogue: bias + sliced BN0 stats + LDS transpose tile
// -> coalesced Y0 [b][n][o] store. (Phase-1 structure verified in rounds 7/8.)
__global__ __launch_bounds__(256) void gemm0_kernel(
    const unsigned short* __restrict__ Wp, const unsigned short* __restrict__ Xp,
    const float* __restrict__ bias0, unsigned short* __restrict__ Y0,
    float* __restrict__ stats) {
  // LDS: 3 staging bufs (A 256x32 @0, B 128x32 @8192) = 36864 ushort (72KB);
  // epilogue aliases it as ytile[128][264] (67.6KB).
  __shared__ unsigned short lds[36864];
  int b = blockIdx.z;
  int n0 = blockIdx.x * 128;
  int t = threadIdx.x;
  int lane = t & 63;
  int w = __builtin_amdgcn_readfirstlane(t >> 6);  // 0..3
  int mi = lane & 15, kq = (lane >> 4) * 8;
  int rq = (lane >> 4) * 4;
  int rA = lane >> 2;
  int cofs = (lane & 3) * 8;
  int slice = ((blockIdx.x << 2) + blockIdx.z) & (NSLICE - 1);

  int mq = (w & 1) * 128;   // m-range 128 per wave (8 frags)
  int nh = (w >> 1) * 64;   // n-range 64 per wave (4 frags)
  const unsigned short* Xb = Xp + ((size_t)b * NPTS + n0) * CIN;

  auto stage = [&](int buf, int k0) {
    unsigned short* dstA = lds + buf * 12288;
    unsigned short* dstB = dstA + 8192;
#pragma unroll
    for (int q = 0; q < 4; q++) {          // A: 256 rows, 64/wave
      int r0 = w * 64 + q * 16;
      const unsigned short* ga = Wp + (size_t)(r0 + rA) * CIN + k0 + cofs;
      __builtin_amdgcn_global_load_lds(
          (const __attribute__((address_space(1))) void*)ga,
          (__attribute__((address_space(3))) void*)(dstA + r0 * 32), 16, 0, 0);
    }
#pragma unroll
    for (int q = 0; q < 2; q++) {          // B: 128 rows, 32/wave
      int r0 = w * 32 + q * 16;
      const unsigned short* gb = Xb + (size_t)(r0 + rA) * CIN + k0 + cofs;
      __builtin_amdgcn_global_load_lds(
          (const __attribute__((address_space(1))) void*)gb,
          (__attribute__((address_space(3))) void*)(dstB + r0 * 32), 16, 0, 0);
    }
  };

  constexpr int NT0 = CIN / 32;  // 12
  f32x4 acc[8][4] = {};

  stage(0, 0);
  stage(1, 32);

#pragma unroll
  for (int kt = 0; kt < NT0; ++kt) {
    if (kt < NT0 - 1) asm volatile("s_waitcnt vmcnt(6)" ::: "memory");
    else              asm volatile("s_waitcnt vmcnt(0)" ::: "memory");
    __builtin_amdgcn_s_barrier();
    asm volatile("" ::: "memory");
    __builtin_amdgcn_sched_barrier(0);

    if (kt + 2 < NT0) stage((kt + 2) % 3, (kt + 2) * 32);

    const unsigned short* Ac = lds + (kt % 3) * 12288;
    const unsigned short* Bc = Ac + 8192;
    bf16x8 af[8], bfr[4];
#pragma unroll
    for (int i = 0; i < 8; i++)
      af[i] = *(const bf16x8*)(Ac + (mq + i * 16 + mi) * 32 + kq);
#pragma unroll
    for (int j = 0; j < 4; j++)
      bfr[j] = *(const bf16x8*)(Bc + (nh + j * 16 + mi) * 32 + kq);
#pragma unroll
    for (int i = 0; i < 8; i++)
#pragma unroll
      for (int j = 0; j < 4; j++)
        acc[i][j] = __builtin_amdgcn_mfma_f32_16x16x32_bf16(
            af[i], bfr[j], acc[i][j], 0, 0, 0);
  }

  __syncthreads();  // staging LDS dead -> reuse as ytile[128][264]
  unsigned short* yt = lds;
  {
    float* sb = stats + slice * 768;        // sum0
    float* qb = sb + 256;                   // sq0
#pragma unroll
    for (int i = 0; i < 8; i++) {
#pragma unroll
      for (int rp = 0; rp < 2; rp++) {
        int m0 = mq + i * 16 + rq + rp * 2;
        float bva = bias0[m0], bvb = bias0[m0 + 1];
        float psA = 0.f, pqA = 0.f, psB = 0.f, pqB = 0.f;
#pragma unroll
        for (int j = 0; j < 4; j++) {
          int n = nh + j * 16 + mi;
          float va = acc[i][j][rp * 2] + bva;
          float vb = acc[i][j][rp * 2 + 1] + bvb;
          psA += va; pqA += va * va; psB += vb; pqB += vb * vb;
          *(unsigned*)&yt[n * 264 + m0] = (unsigned)f2bf(va) | ((unsigned)f2bf(vb) << 16);
        }
#pragma unroll
        for (int off = 1; off < 16; off <<= 1) {
          psA += __shfl_xor(psA, off, 16); pqA += __shfl_xor(pqA, off, 16);
          psB += __shfl_xor(psB, off, 16); pqB += __shfl_xor(pqB, off, 16);
        }
        if (mi == 0) {
          atomicAdd(&sb[m0], psA); atomicAdd(&qb[m0], pqA);
          atomicAdd(&sb[m0 + 1], psB); atomicAdd(&qb[m0 + 1], pqB);
        }
      }
    }
  }
  __syncthreads();

  // coalesced store: Y0[b][n0+row][0..255]
  int row = t >> 1, ch0 = (t & 1) * 128;
  unsigned short* Yr = Y0 + ((size_t)b * NPTS + n0 + row) * H0 + ch0;
#pragma unroll
  for (int j = 0; j < 16; j++) {
    uint4 v = *(const uint4*)&yt[row * 264 + ch0 + j * 8];
    *(uint4*)(Yr + j * 8) = v;
  }
}

// ---------------- GEMM1: Wp1(128x256) x (BN0+ReLU applied on-the-fly to Y0[n][256])
// B reg-staged with fused BN0; double-buffered, 1 barrier per K-step; fused BN1 stats.
__global__ __launch_bounds__(256) void gemm1_kernel(
    const unsigned short* __restrict__ A, const unsigned short* __restrict__ Y0,
    const float* __restrict__ bias, float* __restrict__ out,
    float* __restrict__ stats, const float* __restrict__ gamma0,
    const float* __restrict__ beta0) {
  constexpr int KD = H0;  // 256
  __shared__ unsigned short As[2][4096];
  __shared__ unsigned short Bs[2][4096];
  __shared__ float aS[256], sS[256];
  int b = blockIdx.z;
  int n0 = blockIdx.x * 128;
  int t = threadIdx.x;
  int lane = t & 63;
  int w = __builtin_amdgcn_readfirstlane(t >> 6);
  int mhalf = (w & 1) * 64, nhalf = (w >> 1) * 64;
  int rA = lane >> 2;
  int cofs = (lane & 3) * 8;
  const unsigned short* Yb = Y0 + ((size_t)b * NPTS + n0) * KD;

  // BN0 coefficients from 32-slice stats (channel = t)
  {
    float ms = 0.f, vs = 0.f;
#pragma unroll 8
    for (int sl = 0; sl < NSLICE; sl++) {
      ms += stats[sl * 768 + t];
      vs += stats[sl * 768 + 256 + t];
    }
    const float inv = 1.f / (float)(BATCH * NPTS);
    float mean = ms * inv;
    float var = vs * inv - mean * mean;
    float ia = gamma0[t] * rsqrtf(var + 1e-5f);
    aS[t] = ia; sS[t] = beta0[t] - mean * ia;
  }
  __syncthreads();

  auto stageA = [&](int buf, int k0) {
#pragma unroll
    for (int q = 0; q < 2; q++) {
      int r0 = w * 32 + q * 16;
      const unsigned short* ga = A + (size_t)(r0 + rA) * KD + k0 + cofs;
      __builtin_amdgcn_global_load_lds(
          (const __attribute__((address_space(1))) void*)ga,
          (__attribute__((address_space(3))) void*)(&As[buf][r0 * 32]), 16, 0, 0);
    }
  };
  bf16x8 br[2];
  auto loadB = [&](int k0) {
#pragma unroll
    for (int q = 0; q < 2; q++) {
      int r0 = w * 32 + q * 16;
      br[q] = *(const bf16x8*)(Yb + (size_t)(r0 + rA) * KD + k0 + cofs);
    }
  };
  auto writeB = [&](int buf, int k0) {
#pragma unroll
    for (int q = 0; q < 2; q++) {
      int r0 = w * 32 + q * 16;
      bf16x8 v = br[q], o;
#pragma unroll
      for (int e = 0; e < 8; e++) {
        float f = bf2f((unsigned short)v[e]);
        f = fmaxf(fmaf(f, aS[k0 + cofs + e], sS[k0 + cofs + e]), 0.f);
        o[e] = (short)f2bf(f);
      }
      *(bf16x8*)(&Bs[buf][(r0 + rA) * 32 + cofs]) = o;
    }
  };

  constexpr int NT = KD / 32;  // 8
  f32x4 acc[4][4] = {};
  int mi = lane & 15, kq = (lane >> 4) * 8;

  stageA(0, 0);
  loadB(0);
  int buf = 0;
#pragma unroll
  for (int kt = 0; kt < NT; ++kt) {
    asm volatile("s_waitcnt vmcnt(0)" ::: "memory");   // A(kt) in LDS, B(kt) in regs
    __builtin_amdgcn_sched_barrier(0);
    writeB(buf, kt * 32);                              // BN0+ReLU transform -> LDS
    asm volatile("s_waitcnt lgkmcnt(0)" ::: "memory");
    asm volatile("s_barrier" ::: "memory");
    __builtin_amdgcn_sched_barrier(0);
    if (kt + 1 < NT) { stageA(buf ^ 1, (kt + 1) * 32); loadB((kt + 1) * 32); }

    bf16x8 af[4], bfr[4];
#pragma unroll
    for (int i = 0; i < 4; i++) {
      af[i]  = *(const bf16x8*)(&As[buf][(mhalf + i * 16 + mi) * 32 + kq]);
      bfr[i] = *(const bf16x8*)(&Bs[buf][(nhalf + i * 16 + mi) * 32 + kq]);
    }
#pragma unroll
    for (int mt = 0; mt < 4; mt++)
#pragma unroll
      for (int nt = 0; nt < 4; nt++)
        acc[mt][nt] = __builtin_amdgcn_mfma_f32_16x16x32_bf16(
            af[mt], bfr[nt], acc[mt][nt], 0, 0, 0);
    buf ^= 1;
  }

  int slice = ((blockIdx.x << 2) + blockIdx.z) & (NSLICE - 1);
  float* sb = stats + slice * 768 + 512;  // sum1
  float* qb = stats + slice * 768 + 640;  // sq1
  float* Yo = out + (size_t)b * H1 * NPTS;

  int rq = (lane >> 4) * 4;
#pragma unroll
  for (int mt = 0; mt < 4; mt++) {
#pragma unroll
    for (int r = 0; r < 4; r++) {
      int m = mhalf + mt * 16 + rq + r;
      float bv = bias[m];
      float ps = 0.f, pq = 0.f;
#pragma unroll
      for (int nt = 0; nt < 4; nt++) {
        int n = n0 + nhalf + nt * 16 + mi;
        float v = acc[mt][nt][r] + bv;
        ps += v; pq += v * v;
        Yo[(size_t)m * NPTS + n] = v;
      }
#pragma unroll
      for (int off = 1; off < 16; off <<= 1) {
        ps += __shfl_xor(ps, off, 16);
        pq += __shfl_xor(pq, off, 16);
      }
      if (mi == 0) {
        atomicAdd(&sb[m], ps);
        atomicAdd(&qb[m], pq);
      }
    }
  }
}

// ---------------- final BN+ReLU in-place on d_out (stats from 32 slices) ----------------
__global__ __launch_bounds__(256) void bn_apply_kernel(
    float* __restrict__ Y, const float* __restrict__ stats,
    const float* __restrict__ gamma, const float* __restrict__ beta) {
  __shared__ float sh2[2];
  int idx0 = blockIdx.x * 1024;          // 1024 contiguous fp32 per block
  int c = (idx0 >> 13) & (H1 - 1);       // single channel per block (1024 | 8192)
  int t = threadIdx.x;
  if (t < 32) {
    float ms = stats[t * 768 + 512 + c];
    float vs = stats[t * 768 + 640 + c];
#pragma unroll
    for (int off = 16; off > 0; off >>= 1) {
      ms += __shfl_down(ms, off, 32);
      vs += __shfl_down(vs, off, 32);
    }
    if (t == 0) {
      const float inv = 1.f / (float)(BATCH * NPTS);
      float mean = ms * inv;
      float var = vs * inv - mean * mean;
      float ia = gamma[c] * rsqrtf(var + 1e-5f);
      sh2[0] = ia; sh2[1] = beta[c] - mean * ia;
    }
  }
  __syncthreads();
  float ia = sh2[0], sh = sh2[1];
  int i = idx0 + t * 4;
  float4 v = *(float4*)(Y + i);
  v.x = fmaxf(v.x * ia + sh, 0.f);
  v.y = fmaxf(v.y * ia + sh, 0.f);
  v.z = fmaxf(v.z * ia + sh, 0.f);
  v.w = fmaxf(v.w * ia + sh, 0.f);
  *(float4*)(Y + i) = v;
}

extern "C" void kernel_launch(void* const* d_in, const int* in_sizes, int n_in,
                              void* d_out, int out_size, void* d_ws, size_t ws_size,
                              hipStream_t stream) {
  const float* xyz1    = (const float*)d_in[0];
  const float* xyz2    = (const float*)d_in[1];
  const float* points1 = (const float*)d_in[2];
  const float* points2 = (const float*)d_in[3];
  const float* w0      = (const float*)d_in[4];
  const float* b0      = (const float*)d_in[5];
  const float* gamma0  = (const float*)d_in[6];
  const float* beta0   = (const float*)d_in[7];
  const float* w1      = (const float*)d_in[8];
  const float* b1      = (const float*)d_in[9];
  const float* gamma1  = (const float*)d_in[10];
  const float* beta1   = (const float*)d_in[11];
  float* out = (float*)d_out;

  char* ws = (char*)d_ws;
  unsigned short* p2tb = (unsigned short*)ws;  ws += (size_t)BATCH * SPTS * C2 * 2;   // 4.2 MB
  unsigned short* Xp = (unsigned short*)ws;    ws += (size_t)BATCH * NPTS * CIN * 2;  // 25.2 MB
  unsigned short* Y0 = (unsigned short*)ws;    ws += (size_t)BATCH * NPTS * H0 * 2;   // 16.8 MB ([b][n][o])
  unsigned short* Wp = (unsigned short*)ws;    ws += (size_t)(H0 * CIN + H1 * H0) * 2;
  float4* xyz2p = (float4*)(((uintptr_t)ws + 15) & ~(uintptr_t)15);
  ws = (char*)xyz2p + (size_t)BATCH * SPTS * 16;
  float* stats = (float*)ws;                   ws += (size_t)NSLICE * 768 * 4;  // 96 KB
  // per-slice layout: [0,256)=sum0, [256,512)=sq0, [512,640)=sum1, [640,768)=sq1
  (void)ws_size; (void)in_sizes; (void)n_in; (void)out_size;

  prep_kernel<<<dim3(1208), 256, 0, stream>>>(points2, p2tb, xyz2, xyz2p,
                                              w0, w1, Wp, points1, Xp, stats);
  knn_interp_kernel<<<dim3(NPTS / 64, BATCH), 1024, 0, stream>>>(xyz1, xyz2p, p2tb, Xp);
  gemm0_kernel<<<dim3(NPTS / 128, 1, BATCH), 256, 0, stream>>>(
      Wp, Xp, b0, Y0, stats);
  gemm1_kernel<<<dim3(NPTS / 128, 1, BATCH), 256, 0, stream>>>(
      Wp + H0 * CIN, Y0, b1, out, stats, gamma0, beta0);
  bn_apply_kernel<<<dim3(BATCH * H1 * NPTS / 1024), 256, 0, stream>>>(
      out, stats, gamma1, beta1);
}

// Round 10
// 178.667 us; speedup vs baseline: 2.0752x; 1.0336x over previous
//
#include <hip/hip_runtime.h>
#include <hip/hip_bf16.h>

#define BATCH 4
#define NPTS  8192
#define SPTS  2048
#define C1    128
#define C2    256
#define CIN   384   // C1+C2
#define H0    256
#define H1    128
#define NSLICE 32   // BN-stat accumulator slices

typedef __attribute__((ext_vector_type(8))) short bf16x8;
typedef __attribute__((ext_vector_type(4))) float f32x4;

__device__ __forceinline__ unsigned short f2bf(float x) {
  union { float f; unsigned u; } v; v.f = x;
  unsigned r = v.u + 0x7fff + ((v.u >> 16) & 1);   // RNE
  return (unsigned short)(r >> 16);
}
__device__ __forceinline__ float bf2f(unsigned short u) {
  union { unsigned u; float f; } v; v.u = ((unsigned)u) << 16; return v.f;
}

// ---------------- fused prep: all input-only packing in one launch ----------------
__global__ __launch_bounds__(256) void prep_kernel(
    const float* __restrict__ p2, unsigned short* __restrict__ p2tb,
    const float* __restrict__ xyz2, float4* __restrict__ xp,
    const float* __restrict__ w0, const float* __restrict__ w1,
    unsigned short* __restrict__ Wp,
    const float* __restrict__ p1, unsigned short* __restrict__ Xp,
    float* __restrict__ stats) {
  __shared__ unsigned short shmem[64 * 136];
  int bid = blockIdx.x;
  int t = threadIdx.x;

  if (bid < 512) {  // ---- transpose p2 -> bf16 ----
    int b = bid >> 7, rem = bid & 127;
    int s0 = (rem >> 2) * 64, c0 = (rem & 3) * 64;
    const float* src = p2 + (size_t)b * C2 * SPTS;
    int ss = t & 63, cseg = t >> 6;
#pragma unroll
    for (int i = 0; i < 16; i++) {
      int cc = cseg + i * 4;
      shmem[ss * 72 + cc] = f2bf(src[(size_t)(c0 + cc) * SPTS + s0 + ss]);
    }
    __syncthreads();
    int s = t >> 2, chunk = t & 3;
    uint4 v0 = *(const uint4*)&shmem[s * 72 + chunk * 16];
    uint4 v1 = *(const uint4*)&shmem[s * 72 + chunk * 16 + 8];
    unsigned short* dst = p2tb + (size_t)b * SPTS * C2 + (size_t)(s0 + s) * C2 + c0 + chunk * 16;
    *(uint4*)dst = v0;
    *(uint4*)(dst + 8) = v1;
  } else if (bid < 1024) {  // ---- pack p1 ----
    int b2 = bid - 512;
    int b = b2 >> 7, n0 = (b2 & 127) * 64;
    int nn = t & 63, c4 = t >> 6;
#pragma unroll
    for (int i = 0; i < 32; i++) {
      int c = i * 4 + c4;
      shmem[nn * 136 + c] = f2bf(p1[((size_t)b * C1 + c) * NPTS + n0 + nn]);
    }
    __syncthreads();
    int n = t >> 2;
#pragma unroll
    for (int j = 0; j < 4; j++) {
      int ch = (t & 3) + j * 4;
      uint4 v = *(const uint4*)&shmem[n * 136 + ch * 8];
      *(uint4*)&Xp[((size_t)b * NPTS + n0 + n) * CIN + ch * 8] = v;
    }
  } else if (bid < 1056) {  // ---- prepack xyz2 (pre-negated, doubled) ----
    int idx = (bid - 1024) * 256 + t;
    int b = idx >> 11, s = idx & (SPTS - 1);
    const float* x2 = xyz2 + (size_t)b * 3 * SPTS;
    float x = x2[s], y = x2[SPTS + s], z = x2[2 * SPTS + s];
    xp[idx] = make_float4(-2.f * x, -2.f * y, -2.f * z, x * x + y * y + z * z);
  } else if (bid < 1184) {  // ---- pack weights ----
    int idx = ((bid - 1056) * 256 + t) * 4;
    const float* src = (idx < H0 * CIN) ? (w0 + idx) : (w1 + (idx - H0 * CIN));
    float4 v = *(const float4*)src;
    ushort4 o;
    o.x = f2bf(v.x); o.y = f2bf(v.y); o.z = f2bf(v.z); o.w = f2bf(v.w);
    *(ushort4*)(Wp + idx) = o;
  } else {  // ---- zero BN stat accumulators ----
    int i4 = ((bid - 1184) * 256 + t) * 4;
    if (i4 < NSLICE * 768) *(float4*)(stats + i4) = make_float4(0.f, 0.f, 0.f, 0.f);
  }
}

// branchless top-3 insert: distances via fmin/fmed3, indices via cndmask (EXACT)
#define INS3(d, s, e0, e1, e2, j0, j1, j2)                        \
  {                                                               \
    bool lt0 = (d) < (e0), lt1 = (d) < (e1), lt2 = (d) < (e2);    \
    j2 = lt1 ? (j1) : (lt2 ? (s) : (j2));                         \
    j1 = lt0 ? (j0) : (lt1 ? (s) : (j1));                         \
    j0 = lt0 ? (s) : (j0);                                        \
    e2 = __builtin_amdgcn_fmed3f((d), (e1), (e2));                \
    e1 = __builtin_amdgcn_fmed3f((d), (e0), (e1));                \
    e0 = fminf((d), (e0));                                        \
  }

// ---------------- 3-NN search + fused interpolation ----------------
__global__ __launch_bounds__(1024) void knn_interp_kernel(
    const float* __restrict__ xyz1, const float4* __restrict__ xp,
    const unsigned short* __restrict__ p2tb, unsigned short* __restrict__ Xp) {
  int b = blockIdx.y;
  int t = threadIdx.x;
  int lane = t & 63;
  int w = __builtin_amdgcn_readfirstlane(t >> 6);  // 0..15
  int n = blockIdx.x * 64 + lane;
  const float* x1 = xyz1 + (size_t)b * 3 * NPTS;
  float px = x1[n], py = x1[NPTS + n], pz = x1[2 * NPTS + n];

  const int CHUNK = SPTS / 16;  // 128
  int sbase = w * CHUNK;
  const float4* cp = xp + (size_t)b * SPTS + sbase;

  float d0 = 3e38f, d1 = 3e38f, d2 = 3e38f;
  int i0 = 0, i1 = 0, i2 = 0;
#pragma unroll 8
  for (int j = 0; j < CHUNK; j++) {
    float4 c = cp[j];  // wave-uniform address -> scalar load
    float d = fmaf(c.z, pz, fmaf(c.y, py, fmaf(c.x, px, c.w)));
    int s = sbase + j;
    INS3(d, s, d0, d1, d2, i0, i1, i2);
  }

  __shared__ float dsh[16][64][3];
  __shared__ int   ish[16][64][3];
  __shared__ int   widx[64][3];
  __shared__ float wwgt[64][3];
  dsh[w][lane][0] = d0; dsh[w][lane][1] = d1; dsh[w][lane][2] = d2;
  ish[w][lane][0] = i0; ish[w][lane][1] = i1; ish[w][lane][2] = i2;
  __syncthreads();

  if (t < 256) {  // stage B: 4 groups merge 4 lists each
    int g = t >> 6, q = t & 63;
    float e0 = 3e38f, e1 = 3e38f, e2 = 3e38f;
    int j0 = 0, j1 = 0, j2 = 0;
#pragma unroll
    for (int c = 0; c < 4; c++) {
#pragma unroll
      for (int k = 0; k < 3; k++) {
        float d = dsh[4 * g + c][q][k];
        int s = ish[4 * g + c][q][k];
        INS3(d, s, e0, e1, e2, j0, j1, j2);
      }
    }
    dsh[4 * g][q][0] = e0; dsh[4 * g][q][1] = e1; dsh[4 * g][q][2] = e2;
    ish[4 * g][q][0] = j0; ish[4 * g][q][1] = j1; ish[4 * g][q][2] = j2;
  }
  __syncthreads();

  if (t < 64) {  // stage C: final merge; weights -> LDS
    float e0 = 3e38f, e1 = 3e38f, e2 = 3e38f;
    int j0 = 0, j1 = 0, j2 = 0;
#pragma unroll
    for (int c = 0; c < 4; c++) {
#pragma unroll
      for (int k = 0; k < 3; k++) {
        float d = dsh[4 * c][t][k];
        int s = ish[4 * c][t][k];
        INS3(d, s, e0, e1, e2, j0, j1, j2);
      }
    }
    float qq = fmaf(px, px, fmaf(py, py, pz * pz));
    float r0 = 1.f / (e0 + qq + 1e-8f);
    float r1 = 1.f / (e1 + qq + 1e-8f);
    float r2 = 1.f / (e2 + qq + 1e-8f);
    float rs = 1.f / (r0 + r1 + r2);
    widx[t][0] = j0; widx[t][1] = j1; widx[t][2] = j2;
    wwgt[t][0] = r0 * rs; wwgt[t][1] = r1 * rs; wwgt[t][2] = r2 * rs;
  }
  __syncthreads();

  // ---- fused interpolation ----
  const unsigned short* base = p2tb + (size_t)b * SPTS * C2;
  int c2 = (t & 127) * 2;
  int psub = t >> 7;
  unsigned short* xrow = Xp + ((size_t)b * NPTS + blockIdx.x * 64) * CIN + C1 + c2;
#pragma unroll
  for (int i = 0; i < 8; i++) {
    int pl = psub + i * 8;
    int g0 = widx[pl][0], g1 = widx[pl][1], g2 = widx[pl][2];
    float w0v = wwgt[pl][0], w1v = wwgt[pl][1], w2v = wwgt[pl][2];
    unsigned a0 = *(const unsigned*)(base + (size_t)g0 * C2 + c2);
    unsigned a1 = *(const unsigned*)(base + (size_t)g1 * C2 + c2);
    unsigned a2 = *(const unsigned*)(base + (size_t)g2 * C2 + c2);
    float v0 = w0v * bf2f((unsigned short)a0) + w1v * bf2f((unsigned short)a1) +
               w2v * bf2f((unsigned short)a2);
    float v1 = w0v * bf2f((unsigned short)(a0 >> 16)) + w1v * bf2f((unsigned short)(a1 >> 16)) +
               w2v * bf2f((unsigned short)(a2 >> 16));
    unsigned pk = (unsigned)f2bf(v0) | ((unsigned)f2bf(v1) << 16);
    *(unsigned*)(xrow + (size_t)pl * CIN) = pk;
  }
}

// ---------------- GEMM0 (round-5 version): 128x128 tiles, 512 blocks (2/CU),
// triple-buffered counted-vmcnt; epilogue: bias + sliced BN0 stats + transpose tile
// -> Y0 [b][n][o] bf16.
__global__ __launch_bounds__(256) void gemm0_kernel(
    const unsigned short* __restrict__ A, const unsigned short* __restrict__ X,
    const float* __restrict__ bias, unsigned short* __restrict__ Y0,
    float* __restrict__ stats) {
  constexpr int KD = CIN;  // 384
  __shared__ unsigned short lds[24576];  // 48KB: As[3]@0, Bs[3]@12288; epilogue tile[128][136]
  int b = blockIdx.z;
  int n0 = blockIdx.x * 128;
  int o0 = blockIdx.y * 128;
  int t = threadIdx.x;
  int lane = t & 63;
  int w = __builtin_amdgcn_readfirstlane(t >> 6);
  int mhalf = (w & 1) * 64, nhalf = (w >> 1) * 64;
  const unsigned short* Xb = X + (size_t)b * NPTS * KD;
  int rA = lane >> 2;
  int cofs = (lane & 3) * 8;

  auto stage = [&](int buf, int k0) {
#pragma unroll
    for (int q = 0; q < 2; q++) {
      int r0 = w * 32 + q * 16;
      const unsigned short* ga = A + (size_t)(o0 + r0 + rA) * KD + k0 + cofs;
      __builtin_amdgcn_global_load_lds(
          (const __attribute__((address_space(1))) void*)ga,
          (__attribute__((address_space(3))) void*)(lds + buf * 4096 + r0 * 32), 16, 0, 0);
      const unsigned short* gb = Xb + (size_t)(n0 + r0 + rA) * KD + k0 + cofs;
      __builtin_amdgcn_global_load_lds(
          (const __attribute__((address_space(1))) void*)gb,
          (__attribute__((address_space(3))) void*)(lds + 12288 + buf * 4096 + r0 * 32), 16, 0, 0);
    }
  };

  constexpr int NT = KD / 32;  // 12
  f32x4 acc[4][4] = {};
  int mi = lane & 15, kq = (lane >> 4) * 8;

  stage(0, 0);
  stage(1, 32);

#pragma unroll
  for (int kt = 0; kt < NT; ++kt) {
    if (kt < NT - 1) asm volatile("s_waitcnt vmcnt(4)" ::: "memory");
    else             asm volatile("s_waitcnt vmcnt(0)" ::: "memory");
    __builtin_amdgcn_s_barrier();
    asm volatile("" ::: "memory");
    __builtin_amdgcn_sched_barrier(0);

    if (kt + 2 < NT) stage((kt + 2) % 3, (kt + 2) * 32);

    const unsigned short* Ac = lds + (kt % 3) * 4096;
    const unsigned short* Bc = lds + 12288 + (kt % 3) * 4096;
    bf16x8 af[4], bfr[4];
#pragma unroll
    for (int i = 0; i < 4; i++) {
      af[i]  = *(const bf16x8*)(Ac + (mhalf + i * 16 + mi) * 32 + kq);
      bfr[i] = *(const bf16x8*)(Bc + (nhalf + i * 16 + mi) * 32 + kq);
    }
#pragma unroll
    for (int mt = 0; mt < 4; mt++)
#pragma unroll
      for (int nt = 0; nt < 4; nt++)
        acc[mt][nt] = __builtin_amdgcn_mfma_f32_16x16x32_bf16(
            af[mt], bfr[nt], acc[mt][nt], 0, 0, 0);
  }

  __syncthreads();  // all MFMA consumed LDS; safe to reuse as transpose tile

  int slice = ((blockIdx.x << 2) + blockIdx.z) & (NSLICE - 1);
  float* sb = stats + slice * 768;        // sum0
  float* qb = stats + slice * 768 + 256;  // sq0

  int rq = (lane >> 4) * 4;
#pragma unroll
  for (int mt = 0; mt < 4; mt++) {
#pragma unroll
    for (int r = 0; r < 4; r++) {
      int ml = mhalf + mt * 16 + rq + r;
      float bv = bias[o0 + ml];
      float ps = 0.f, pq = 0.f;
#pragma unroll
      for (int nt = 0; nt < 4; nt++) {
        int nl = nhalf + nt * 16 + mi;
        float v = acc[mt][nt][r] + bv;
        ps += v; pq += v * v;
        lds[nl * 136 + ml] = f2bf(v);   // [n_local][m_local] transpose tile
      }
#pragma unroll
      for (int off = 1; off < 16; off <<= 1) {
        ps += __shfl_xor(ps, off, 16);
        pq += __shfl_xor(pq, off, 16);
      }
      if (mi == 0) {
        atomicAdd(&sb[o0 + ml], ps);
        atomicAdd(&qb[o0 + ml], pq);
      }
    }
  }
  __syncthreads();

  // coalesced store: Y0[b][n0+row][o0 .. o0+127]
  int row = t >> 1, ch0 = (t & 1) * 64;
  unsigned short* Yr = Y0 + ((size_t)b * NPTS + n0 + row) * H0 + o0 + ch0;
#pragma unroll
  for (int j = 0; j < 8; j++) {
    uint4 v = *(const uint4*)&lds[row * 136 + ch0 + j * 8];
    *(uint4*)(Yr + j * 8) = v;
  }
}

// ---------------- GEMM1: 64-wide n-tiles (512 blocks, 2/CU); B reg-staged with
// fused BN0+ReLU; fused BN1 stats; y1 output in bf16 (halves write + bn_apply read).
__global__ __launch_bounds__(256) void gemm1_kernel(
    const unsigned short* __restrict__ A, const unsigned short* __restrict__ Y0,
    const float* __restrict__ bias, unsigned short* __restrict__ y1,
    float* __restrict__ stats, const float* __restrict__ gamma0,
    const float* __restrict__ beta0) {
  constexpr int KD = H0;  // 256
  __shared__ unsigned short As[2][4096];   // 128 x 32
  __shared__ unsigned short Bs[2][2048];   // 64 x 32
  __shared__ float aS[256], sS[256];
  int b = blockIdx.z;
  int n0 = blockIdx.x * 64;
  int t = threadIdx.x;
  int lane = t & 63;
  int w = __builtin_amdgcn_readfirstlane(t >> 6);
  int mhalf = (w & 1) * 64;       // m: 2 x 64
  int nhalf = (w >> 1) * 32;      // n: 2 x 32
  int rA = lane >> 2;
  int cofs = (lane & 3) * 8;
  const unsigned short* Yb = Y0 + ((size_t)b * NPTS + n0) * KD;

  // BN0 coefficients from 32-slice stats (channel = t)
  {
    float ms = 0.f, vs = 0.f;
#pragma unroll 8
    for (int sl = 0; sl < NSLICE; sl++) {
      ms += stats[sl * 768 + t];
      vs += stats[sl * 768 + 256 + t];
    }
    const float inv = 1.f / (float)(BATCH * NPTS);
    float mean = ms * inv;
    float var = vs * inv - mean * mean;
    float ia = gamma0[t] * rsqrtf(var + 1e-5f);
    aS[t] = ia; sS[t] = beta0[t] - mean * ia;
  }
  __syncthreads();

  auto stageA = [&](int buf, int k0) {
#pragma unroll
    for (int q = 0; q < 2; q++) {
      int r0 = w * 32 + q * 16;
      const unsigned short* ga = A + (size_t)(r0 + rA) * KD + k0 + cofs;
      __builtin_amdgcn_global_load_lds(
          (const __attribute__((address_space(1))) void*)ga,
          (__attribute__((address_space(3))) void*)(&As[buf][r0 * 32]), 16, 0, 0);
    }
  };
  bf16x8 br;
  auto loadB = [&](int k0) {   // 64 rows x 32 cols: 1 bf16x8 per thread
    br = *(const bf16x8*)(Yb + (size_t)(w * 16 + rA) * KD + k0 + cofs);
  };
  auto writeB = [&](int buf, int k0) {
    bf16x8 v = br, o;
#pragma unroll
    for (int e = 0; e < 8; e++) {
      float f = bf2f((unsigned short)v[e]);
      f = fmaxf(fmaf(f, aS[k0 + cofs + e], sS[k0 + cofs + e]), 0.f);
      o[e] = (short)f2bf(f);
    }
    *(bf16x8*)(&Bs[buf][(w * 16 + rA) * 32 + cofs]) = o;
  };

  constexpr int NT = KD / 32;  // 8
  f32x4 acc[4][2] = {};
  int mi = lane & 15, kq = (lane >> 4) * 8;

  stageA(0, 0);
  loadB(0);
  int buf = 0;
#pragma unroll
  for (int kt = 0; kt < NT; ++kt) {
    asm volatile("s_waitcnt vmcnt(0)" ::: "memory");   // A(kt) in LDS, B(kt) in regs
    __builtin_amdgcn_sched_barrier(0);
    writeB(buf, kt * 32);                              // BN0+ReLU transform -> LDS
    asm volatile("s_waitcnt lgkmcnt(0)" ::: "memory");
    asm volatile("s_barrier" ::: "memory");
    __builtin_amdgcn_sched_barrier(0);
    if (kt + 1 < NT) { stageA(buf ^ 1, (kt + 1) * 32); loadB((kt + 1) * 32); }

    bf16x8 af[4], bfr[2];
#pragma unroll
    for (int i = 0; i < 4; i++)
      af[i] = *(const bf16x8*)(&As[buf][(mhalf + i * 16 + mi) * 32 + kq]);
#pragma unroll
    for (int j = 0; j < 2; j++)
      bfr[j] = *(const bf16x8*)(&Bs[buf][(nhalf + j * 16 + mi) * 32 + kq]);
#pragma unroll
    for (int mt = 0; mt < 4; mt++)
#pragma unroll
      for (int nt = 0; nt < 2; nt++)
        acc[mt][nt] = __builtin_amdgcn_mfma_f32_16x16x32_bf16(
            af[mt], bfr[nt], acc[mt][nt], 0, 0, 0);
    buf ^= 1;
  }

  int slice = ((blockIdx.x << 2) + blockIdx.z) & (NSLICE - 1);
  float* sb = stats + slice * 768 + 512;  // sum1
  float* qb = stats + slice * 768 + 640;  // sq1
  unsigned short* Yo = y1 + (size_t)b * H1 * NPTS;

  int rq = (lane >> 4) * 4;
#pragma unroll
  for (int mt = 0; mt < 4; mt++) {
#pragma unroll
    for (int r = 0; r < 4; r++) {
      int m = mhalf + mt * 16 + rq + r;
      float bv = bias[m];
      float ps = 0.f, pq = 0.f;
#pragma unroll
      for (int nt = 0; nt < 2; nt++) {
        int n = n0 + nhalf + nt * 16 + mi;
        float v = acc[mt][nt][r] + bv;
        ps += v; pq += v * v;
        Yo[(size_t)m * NPTS + n] = f2bf(v);
      }
#pragma unroll
      for (int off = 1; off < 16; off <<= 1) {
        ps += __shfl_xor(ps, off, 16);
        pq += __shfl_xor(pq, off, 16);
      }
      if (mi == 0) {
        atomicAdd(&sb[m], ps);
        atomicAdd(&qb[m], pq);
      }
    }
  }
}

// ---------------- final BN+ReLU: read y1 bf16, write out fp32 ----------------
__global__ __launch_bounds__(256) void bn_apply_kernel(
    const unsigned short* __restrict__ y1, float* __restrict__ out,
    const float* __restrict__ stats, const float* __restrict__ gamma,
    const float* __restrict__ beta) {
  __shared__ float sh2[2];
  int idx0 = blockIdx.x * 1024;          // 1024 contiguous elems per block
  int c = (idx0 >> 13) & (H1 - 1);       // single channel per block (1024 | 8192)
  int t = threadIdx.x;
  if (t < 32) {
    float ms = stats[t * 768 + 512 + c];
    float vs = stats[t * 768 + 640 + c];
#pragma unroll
    for (int off = 16; off > 0; off >>= 1) {
      ms += __shfl_down(ms, off, 32);
      vs += __shfl_down(vs, off, 32);
    }
    if (t == 0) {
      const float inv = 1.f / (float)(BATCH * NPTS);
      float mean = ms * inv;
      float var = vs * inv - mean * mean;
      float ia = gamma[c] * rsqrtf(var + 1e-5f);
      sh2[0] = ia; sh2[1] = beta[c] - mean * ia;
    }
  }
  __syncthreads();
  float ia = sh2[0], sh = sh2[1];
  int i = idx0 + t * 4;
  ushort4 v = *(const ushort4*)(y1 + i);
  float4 o;
  o.x = fmaxf(fmaf(bf2f(v.x), ia, sh), 0.f);
  o.y = fmaxf(fmaf(bf2f(v.y), ia, sh), 0.f);
  o.z = fmaxf(fmaf(bf2f(v.z), ia, sh), 0.f);
  o.w = fmaxf(fmaf(bf2f(v.w), ia, sh), 0.f);
  *(float4*)(out + i) = o;
}

extern "C" void kernel_launch(void* const* d_in, const int* in_sizes, int n_in,
                              void* d_out, int out_size, void* d_ws, size_t ws_size,
                              hipStream_t stream) {
  const float* xyz1    = (const float*)d_in[0];
  const float* xyz2    = (const float*)d_in[1];
  const float* points1 = (const float*)d_in[2];
  const float* points2 = (const float*)d_in[3];
  const float* w0      = (const float*)d_in[4];
  const float* b0      = (const float*)d_in[5];
  const float* gamma0  = (const float*)d_in[6];
  const float* beta0   = (const float*)d_in[7];
  const float* w1      = (const float*)d_in[8];
  const float* b1      = (const float*)d_in[9];
  const float* gamma1  = (const float*)d_in[10];
  const float* beta1   = (const float*)d_in[11];
  float* out = (float*)d_out;

  char* ws = (char*)d_ws;
  unsigned short* p2tb = (unsigned short*)ws;  ws += (size_t)BATCH * SPTS * C2 * 2;   // 4.2 MB
  unsigned short* Xp = (unsigned short*)ws;    ws += (size_t)BATCH * NPTS * CIN * 2;  // 25.2 MB
  unsigned short* Y0 = (unsigned short*)ws;    ws += (size_t)BATCH * NPTS * H0 * 2;   // 16.8 MB ([b][n][o])
  unsigned short* y1 = (unsigned short*)ws;    ws += (size_t)BATCH * H1 * NPTS * 2;   // 8.4 MB ([b][m][n])
  unsigned short* Wp = (unsigned short*)ws;    ws += (size_t)(H0 * CIN + H1 * H0) * 2;
  float4* xyz2p = (float4*)(((uintptr_t)ws + 15) & ~(uintptr_t)15);
  ws = (char*)xyz2p + (size_t)BATCH * SPTS * 16;
  float* stats = (float*)ws;                   ws += (size_t)NSLICE * 768 * 4;  // 96 KB
  // per-slice layout: [0,256)=sum0, [256,512)=sq0, [512,640)=sum1, [640,768)=sq1
  (void)ws_size; (void)in_sizes; (void)n_in; (void)out_size;

  prep_kernel<<<dim3(1208), 256, 0, stream>>>(points2, p2tb, xyz2, xyz2p,
                                              w0, w1, Wp, points1, Xp, stats);
  knn_interp_kernel<<<dim3(NPTS / 64, BATCH), 1024, 0, stream>>>(xyz1, xyz2p, p2tb, Xp);
  gemm0_kernel<<<dim3(NPTS / 128, H0 / 128, BATCH), 256, 0, stream>>>(
      Wp, Xp, b0, Y0, stats);
  gemm1_kernel<<<dim3(NPTS / 64, 1, BATCH), 256, 0, stream>>>(
      Wp + H0 * CIN, Y0, b1, y1, stats, gamma0, beta0);
  bn_apply_kernel<<<dim3(BATCH * H1 * NPTS / 1024), 256, 0, stream>>>(
      y1, out, stats, gamma1, beta1);
}

// Round 11
// 176.837 us; speedup vs baseline: 2.0967x; 1.0104x over previous
//
#include <hip/hip_runtime.h>
#include <hip/hip_bf16.h>

#define BATCH 4
#define NPTS  8192
#define SPTS  2048
#define C1    128
#define C2    256
#define CIN   384   // C1+C2
#define H0    256
#define H1    128
#define NSLICE 32   // BN-stat accumulator slices

typedef __attribute__((ext_vector_type(8))) short bf16x8;
typedef __attribute__((ext_vector_type(4))) float f32x4;

__device__ __forceinline__ unsigned short f2bf(float x) {
  union { float f; unsigned u; } v; v.f = x;
  unsigned r = v.u + 0x7fff + ((v.u >> 16) & 1);   // RNE
  return (unsigned short)(r >> 16);
}
__device__ __forceinline__ float bf2f(unsigned short u) {
  union { unsigned u; float f; } v; v.u = ((unsigned)u) << 16; return v.f;
}

// ---------------- fused prep: all input-only packing in one launch ----------------
__global__ __launch_bounds__(256) void prep_kernel(
    const float* __restrict__ p2, unsigned short* __restrict__ p2tb,
    const float* __restrict__ xyz2, float4* __restrict__ xp,
    const float* __restrict__ w0, const float* __restrict__ w1,
    unsigned short* __restrict__ Wp,
    const float* __restrict__ p1, unsigned short* __restrict__ Xp,
    float* __restrict__ stats) {
  __shared__ unsigned short shmem[64 * 136];
  int bid = blockIdx.x;
  int t = threadIdx.x;

  if (bid < 512) {  // ---- transpose p2 -> bf16 ----
    int b = bid >> 7, rem = bid & 127;
    int s0 = (rem >> 2) * 64, c0 = (rem & 3) * 64;
    const float* src = p2 + (size_t)b * C2 * SPTS;
    int ss = t & 63, cseg = t >> 6;
#pragma unroll
    for (int i = 0; i < 16; i++) {
      int cc = cseg + i * 4;
      shmem[ss * 72 + cc] = f2bf(src[(size_t)(c0 + cc) * SPTS + s0 + ss]);
    }
    __syncthreads();
    int s = t >> 2, chunk = t & 3;
    uint4 v0 = *(const uint4*)&shmem[s * 72 + chunk * 16];
    uint4 v1 = *(const uint4*)&shmem[s * 72 + chunk * 16 + 8];
    unsigned short* dst = p2tb + (size_t)b * SPTS * C2 + (size_t)(s0 + s) * C2 + c0 + chunk * 16;
    *(uint4*)dst = v0;
    *(uint4*)(dst + 8) = v1;
  } else if (bid < 1024) {  // ---- pack p1 ----
    int b2 = bid - 512;
    int b = b2 >> 7, n0 = (b2 & 127) * 64;
    int nn = t & 63, c4 = t >> 6;
#pragma unroll
    for (int i = 0; i < 32; i++) {
      int c = i * 4 + c4;
      shmem[nn * 136 + c] = f2bf(p1[((size_t)b * C1 + c) * NPTS + n0 + nn]);
    }
    __syncthreads();
    int n = t >> 2;
#pragma unroll
    for (int j = 0; j < 4; j++) {
      int ch = (t & 3) + j * 4;
      uint4 v = *(const uint4*)&shmem[n * 136 + ch * 8];
      *(uint4*)&Xp[((size_t)b * NPTS + n0 + n) * CIN + ch * 8] = v;
    }
  } else if (bid < 1056) {  // ---- prepack xyz2 (pre-negated, doubled) ----
    int idx = (bid - 1024) * 256 + t;
    int b = idx >> 11, s = idx & (SPTS - 1);
    const float* x2 = xyz2 + (size_t)b * 3 * SPTS;
    float x = x2[s], y = x2[SPTS + s], z = x2[2 * SPTS + s];
    xp[idx] = make_float4(-2.f * x, -2.f * y, -2.f * z, x * x + y * y + z * z);
  } else if (bid < 1184) {  // ---- pack weights ----
    int idx = ((bid - 1056) * 256 + t) * 4;
    const float* src = (idx < H0 * CIN) ? (w0 + idx) : (w1 + (idx - H0 * CIN));
    float4 v = *(const float4*)src;
    ushort4 o;
    o.x = f2bf(v.x); o.y = f2bf(v.y); o.z = f2bf(v.z); o.w = f2bf(v.w);
    *(ushort4*)(Wp + idx) = o;
  } else {  // ---- zero BN stat accumulators ----
    int i4 = ((bid - 1184) * 256 + t) * 4;
    if (i4 < NSLICE * 768) *(float4*)(stats + i4) = make_float4(0.f, 0.f, 0.f, 0.f);
  }
}

// branchless top-3 insert: distances via fmin/fmed3, indices via cndmask (EXACT)
#define INS3(d, s, e0, e1, e2, j0, j1, j2)                        \
  {                                                               \
    bool lt0 = (d) < (e0), lt1 = (d) < (e1), lt2 = (d) < (e2);    \
    j2 = lt1 ? (j1) : (lt2 ? (s) : (j2));                         \
    j1 = lt0 ? (j0) : (lt1 ? (s) : (j1));                         \
    j0 = lt0 ? (s) : (j0);                                        \
    e2 = __builtin_amdgcn_fmed3f((d), (e1), (e2));                \
    e1 = __builtin_amdgcn_fmed3f((d), (e0), (e1));                \
    e0 = fminf((d), (e0));                                        \
  }

// ---------------- 3-NN search + fused interpolation ----------------
__global__ __launch_bounds__(1024) void knn_interp_kernel(
    const float* __restrict__ xyz1, const float4* __restrict__ xp,
    const unsigned short* __restrict__ p2tb, unsigned short* __restrict__ Xp) {
  int b = blockIdx.y;
  int t = threadIdx.x;
  int lane = t & 63;
  int w = __builtin_amdgcn_readfirstlane(t >> 6);  // 0..15
  int n = blockIdx.x * 64 + lane;
  const float* x1 = xyz1 + (size_t)b * 3 * NPTS;
  float px = x1[n], py = x1[NPTS + n], pz = x1[2 * NPTS + n];

  const int CHUNK = SPTS / 16;  // 128
  int sbase = w * CHUNK;
  const float4* cp = xp + (size_t)b * SPTS + sbase;

  float d0 = 3e38f, d1 = 3e38f, d2 = 3e38f;
  int i0 = 0, i1 = 0, i2 = 0;
#pragma unroll 8
  for (int j = 0; j < CHUNK; j++) {
    float4 c = cp[j];  // wave-uniform address -> scalar load
    float d = fmaf(c.z, pz, fmaf(c.y, py, fmaf(c.x, px, c.w)));
    int s = sbase + j;
    INS3(d, s, d0, d1, d2, i0, i1, i2);
  }

  __shared__ float dsh[16][64][3];
  __shared__ int   ish[16][64][3];
  __shared__ int   widx[64][3];
  __shared__ float wwgt[64][3];
  dsh[w][lane][0] = d0; dsh[w][lane][1] = d1; dsh[w][lane][2] = d2;
  ish[w][lane][0] = i0; ish[w][lane][1] = i1; ish[w][lane][2] = i2;
  __syncthreads();

  if (t < 256) {  // stage B: 4 groups merge 4 lists each
    int g = t >> 6, q = t & 63;
    float e0 = 3e38f, e1 = 3e38f, e2 = 3e38f;
    int j0 = 0, j1 = 0, j2 = 0;
#pragma unroll
    for (int c = 0; c < 4; c++) {
#pragma unroll
      for (int k = 0; k < 3; k++) {
        float d = dsh[4 * g + c][q][k];
        int s = ish[4 * g + c][q][k];
        INS3(d, s, e0, e1, e2, j0, j1, j2);
      }
    }
    dsh[4 * g][q][0] = e0; dsh[4 * g][q][1] = e1; dsh[4 * g][q][2] = e2;
    ish[4 * g][q][0] = j0; ish[4 * g][q][1] = j1; ish[4 * g][q][2] = j2;
  }
  __syncthreads();

  if (t < 64) {  // stage C: final merge; weights -> LDS
    float e0 = 3e38f, e1 = 3e38f, e2 = 3e38f;
    int j0 = 0, j1 = 0, j2 = 0;
#pragma unroll
    for (int c = 0; c < 4; c++) {
#pragma unroll
      for (int k = 0; k < 3; k++) {
        float d = dsh[4 * c][t][k];
        int s = ish[4 * c][t][k];
        INS3(d, s, e0, e1, e2, j0, j1, j2);
      }
    }
    float qq = fmaf(px, px, fmaf(py, py, pz * pz));
    float r0 = 1.f / (e0 + qq + 1e-8f);
    float r1 = 1.f / (e1 + qq + 1e-8f);
    float r2 = 1.f / (e2 + qq + 1e-8f);
    float rs = 1.f / (r0 + r1 + r2);
    widx[t][0] = j0; widx[t][1] = j1; widx[t][2] = j2;
    wwgt[t][0] = r0 * rs; wwgt[t][1] = r1 * rs; wwgt[t][2] = r2 * rs;
  }
  __syncthreads();

  // ---- fused interpolation ----
  const unsigned short* base = p2tb + (size_t)b * SPTS * C2;
  int c2 = (t & 127) * 2;
  int psub = t >> 7;
  unsigned short* xrow = Xp + ((size_t)b * NPTS + blockIdx.x * 64) * CIN + C1 + c2;
#pragma unroll
  for (int i = 0; i < 8; i++) {
    int pl = psub + i * 8;
    int g0 = widx[pl][0], g1 = widx[pl][1], g2 = widx[pl][2];
    float w0v = wwgt[pl][0], w1v = wwgt[pl][1], w2v = wwgt[pl][2];
    unsigned a0 = *(const unsigned*)(base + (size_t)g0 * C2 + c2);
    unsigned a1 = *(const unsigned*)(base + (size_t)g1 * C2 + c2);
    unsigned a2 = *(const unsigned*)(base + (size_t)g2 * C2 + c2);
    float v0 = w0v * bf2f((unsigned short)a0) + w1v * bf2f((unsigned short)a1) +
               w2v * bf2f((unsigned short)a2);
    float v1 = w0v * bf2f((unsigned short)(a0 >> 16)) + w1v * bf2f((unsigned short)(a1 >> 16)) +
               w2v * bf2f((unsigned short)(a2 >> 16));
    unsigned pk = (unsigned)f2bf(v0) | ((unsigned)f2bf(v1) << 16);
    *(unsigned*)(xrow + (size_t)pl * CIN) = pk;
  }
}

// ---------------- GEMM0: 128x128 tiles, 512 blocks (2/CU), triple-buffered
// counted-vmcnt; epilogue: bias + sliced BN0 stats + transpose tile -> Y0 bf16.
__global__ __launch_bounds__(256) void gemm0_kernel(
    const unsigned short* __restrict__ A, const unsigned short* __restrict__ X,
    const float* __restrict__ bias, unsigned short* __restrict__ Y0,
    float* __restrict__ stats) {
  constexpr int KD = CIN;  // 384
  __shared__ unsigned short lds[24576];  // 48KB: As[3]@0, Bs[3]@12288; epilogue tile[128][136]
  int b = blockIdx.z;
  int n0 = blockIdx.x * 128;
  int o0 = blockIdx.y * 128;
  int t = threadIdx.x;
  int lane = t & 63;
  int w = __builtin_amdgcn_readfirstlane(t >> 6);
  int mhalf = (w & 1) * 64, nhalf = (w >> 1) * 64;
  const unsigned short* Xb = X + (size_t)b * NPTS * KD;
  int rA = lane >> 2;
  int cofs = (lane & 3) * 8;

  auto stage = [&](int buf, int k0) {
#pragma unroll
    for (int q = 0; q < 2; q++) {
      int r0 = w * 32 + q * 16;
      const unsigned short* ga = A + (size_t)(o0 + r0 + rA) * KD + k0 + cofs;
      __builtin_amdgcn_global_load_lds(
          (const __attribute__((address_space(1))) void*)ga,
          (__attribute__((address_space(3))) void*)(lds + buf * 4096 + r0 * 32), 16, 0, 0);
      const unsigned short* gb = Xb + (size_t)(n0 + r0 + rA) * KD + k0 + cofs;
      __builtin_amdgcn_global_load_lds(
          (const __attribute__((address_space(1))) void*)gb,
          (__attribute__((address_space(3))) void*)(lds + 12288 + buf * 4096 + r0 * 32), 16, 0, 0);
    }
  };

  constexpr int NT = KD / 32;  // 12
  f32x4 acc[4][4] = {};
  int mi = lane & 15, kq = (lane >> 4) * 8;

  stage(0, 0);
  stage(1, 32);

#pragma unroll
  for (int kt = 0; kt < NT; ++kt) {
    if (kt < NT - 1) asm volatile("s_waitcnt vmcnt(4)" ::: "memory");
    else             asm volatile("s_waitcnt vmcnt(0)" ::: "memory");
    __builtin_amdgcn_s_barrier();
    asm volatile("" ::: "memory");
    __builtin_amdgcn_sched_barrier(0);

    if (kt + 2 < NT) stage((kt + 2) % 3, (kt + 2) * 32);

    const unsigned short* Ac = lds + (kt % 3) * 4096;
    const unsigned short* Bc = lds + 12288 + (kt % 3) * 4096;
    bf16x8 af[4], bfr[4];
#pragma unroll
    for (int i = 0; i < 4; i++) {
      af[i]  = *(const bf16x8*)(Ac + (mhalf + i * 16 + mi) * 32 + kq);
      bfr[i] = *(const bf16x8*)(Bc + (nhalf + i * 16 + mi) * 32 + kq);
    }
#pragma unroll
    for (int mt = 0; mt < 4; mt++)
#pragma unroll
      for (int nt = 0; nt < 4; nt++)
        acc[mt][nt] = __builtin_amdgcn_mfma_f32_16x16x32_bf16(
            af[mt], bfr[nt], acc[mt][nt], 0, 0, 0);
  }

  __syncthreads();  // all MFMA consumed LDS; safe to reuse as transpose tile

  int slice = ((blockIdx.x << 2) + blockIdx.z) & (NSLICE - 1);
  float* sb = stats + slice * 768;        // sum0
  float* qb = stats + slice * 768 + 256;  // sq0

  int rq = (lane >> 4) * 4;
#pragma unroll
  for (int mt = 0; mt < 4; mt++) {
#pragma unroll
    for (int r = 0; r < 4; r++) {
      int ml = mhalf + mt * 16 + rq + r;
      float bv = bias[o0 + ml];
      float ps = 0.f, pq = 0.f;
#pragma unroll
      for (int nt = 0; nt < 4; nt++) {
        int nl = nhalf + nt * 16 + mi;
        float v = acc[mt][nt][r] + bv;
        ps += v; pq += v * v;
        lds[nl * 136 + ml] = f2bf(v);   // [n_local][m_local] transpose tile
      }
#pragma unroll
      for (int off = 1; off < 16; off <<= 1) {
        ps += __shfl_xor(ps, off, 16);
        pq += __shfl_xor(pq, off, 16);
      }
      if (mi == 0) {
        atomicAdd(&sb[o0 + ml], ps);
        atomicAdd(&qb[o0 + ml], pq);
      }
    }
  }
  __syncthreads();

  // coalesced store: Y0[b][n0+row][o0 .. o0+127]
  int row = t >> 1, ch0 = (t & 1) * 64;
  unsigned short* Yr = Y0 + ((size_t)b * NPTS + n0 + row) * H0 + o0 + ch0;
#pragma unroll
  for (int j = 0; j < 8; j++) {
    uint4 v = *(const uint4*)&lds[row * 136 + ch0 + j * 8];
    *(uint4*)(Yr + j * 8) = v;
  }
}

// ---------------- GEMM1: 64-wide n-tiles (512 blocks, 2/CU); B reg-staged with
// fused BN0+ReLU; 2-deep counted-vmcnt pipeline (3 VMEM ops/step -> vmcnt(3));
// As triple-buffered, Bs double-buffered; fused BN1 stats; y1 bf16 out.
__global__ __launch_bounds__(256) void gemm1_kernel(
    const unsigned short* __restrict__ A, const unsigned short* __restrict__ Y0,
    const float* __restrict__ bias, unsigned short* __restrict__ y1,
    float* __restrict__ stats, const float* __restrict__ gamma0,
    const float* __restrict__ beta0) {
  constexpr int KD = H0;  // 256
  __shared__ unsigned short As[3][4096];   // 128 x 32 x3
  __shared__ unsigned short Bs[2][2048];   // 64 x 32 x2
  __shared__ float aS[256], sS[256];
  int b = blockIdx.z;
  int n0 = blockIdx.x * 64;
  int t = threadIdx.x;
  int lane = t & 63;
  int w = __builtin_amdgcn_readfirstlane(t >> 6);
  int mhalf = (w & 1) * 64;       // m: 2 x 64
  int nhalf = (w >> 1) * 32;      // n: 2 x 32
  int rA = lane >> 2;
  int cofs = (lane & 3) * 8;
  const unsigned short* Yb = Y0 + ((size_t)b * NPTS + n0) * KD;

  // BN0 coefficients from 32-slice stats (channel = t)
  {
    float ms = 0.f, vs = 0.f;
#pragma unroll 8
    for (int sl = 0; sl < NSLICE; sl++) {
      ms += stats[sl * 768 + t];
      vs += stats[sl * 768 + 256 + t];
    }
    const float inv = 1.f / (float)(BATCH * NPTS);
    float mean = ms * inv;
    float var = vs * inv - mean * mean;
    float ia = gamma0[t] * rsqrtf(var + 1e-5f);
    aS[t] = ia; sS[t] = beta0[t] - mean * ia;
  }
  __syncthreads();

  auto stageA = [&](int buf, int k0) {   // 2 VMEM ops
#pragma unroll
    for (int q = 0; q < 2; q++) {
      int r0 = w * 32 + q * 16;
      const unsigned short* ga = A + (size_t)(r0 + rA) * KD + k0 + cofs;
      __builtin_amdgcn_global_load_lds(
          (const __attribute__((address_space(1))) void*)ga,
          (__attribute__((address_space(3))) void*)(&As[buf][r0 * 32]), 16, 0, 0);
    }
  };
  bf16x8 br[2];
  auto loadB = [&](int slot, int k0) {   // 1 VMEM op
    br[slot] = *(const bf16x8*)(Yb + (size_t)(w * 16 + rA) * KD + k0 + cofs);
  };
  auto writeB = [&](int buf, int slot, int k0) {
    bf16x8 v = br[slot], o;
#pragma unroll
    for (int e = 0; e < 8; e++) {
      float f = bf2f((unsigned short)v[e]);
      f = fmaxf(fmaf(f, aS[k0 + cofs + e], sS[k0 + cofs + e]), 0.f);
      o[e] = (short)f2bf(f);
    }
    *(bf16x8*)(&Bs[buf][(w * 16 + rA) * 32 + cofs]) = o;
  };

  constexpr int NT = KD / 32;  // 8
  f32x4 acc[4][2] = {};
  int mi = lane & 15, kq = (lane >> 4) * 8;

  // prologue: steps 0 and 1 in flight (6 VMEM ops)
  stageA(0, 0);      loadB(0, 0);
  stageA(1, 32);     loadB(1, 32);

#pragma unroll
  for (int kt = 0; kt < NT; ++kt) {
    // oldest step's 3 ops landed; newest step (kt+1) stays in flight
    if (kt < NT - 1) asm volatile("s_waitcnt vmcnt(3)" ::: "memory");
    else             asm volatile("s_waitcnt vmcnt(0)" ::: "memory");
    __builtin_amdgcn_sched_barrier(0);
    writeB(kt & 1, kt & 1, kt * 32);       // BN0+ReLU transform -> Bs[kt&1]
    asm volatile("s_waitcnt lgkmcnt(0)" ::: "memory");
    asm volatile("s_barrier" ::: "memory");
    __builtin_amdgcn_sched_barrier(0);
    // issue step kt+2 (As slot (kt+2)%3 free: readers of it finished at kt-1;
    // br slot kt&1 free: consumed by writeB above)
    if (kt + 2 < NT) { stageA((kt + 2) % 3, (kt + 2) * 32); loadB(kt & 1, (kt + 2) * 32); }

    bf16x8 af[4], bfr[2];
#pragma unroll
    for (int i = 0; i < 4; i++)
      af[i] = *(const bf16x8*)(&As[kt % 3][(mhalf + i * 16 + mi) * 32 + kq]);
#pragma unroll
    for (int j = 0; j < 2; j++)
      bfr[j] = *(const bf16x8*)(&Bs[kt & 1][(nhalf + j * 16 + mi) * 32 + kq]);
#pragma unroll
    for (int mt = 0; mt < 4; mt++)
#pragma unroll
      for (int nt = 0; nt < 2; nt++)
        acc[mt][nt] = __builtin_amdgcn_mfma_f32_16x16x32_bf16(
            af[mt], bfr[nt], acc[mt][nt], 0, 0, 0);
  }

  int slice = ((blockIdx.x << 2) + blockIdx.z) & (NSLICE - 1);
  float* sb = stats + slice * 768 + 512;  // sum1
  float* qb = stats + slice * 768 + 640;  // sq1
  unsigned short* Yo = y1 + (size_t)b * H1 * NPTS;

  int rq = (lane >> 4) * 4;
#pragma unroll
  for (int mt = 0; mt < 4; mt++) {
#pragma unroll
    for (int r = 0; r < 4; r++) {
      int m = mhalf + mt * 16 + rq + r;
      float bv = bias[m];
      float ps = 0.f, pq = 0.f;
#pragma unroll
      for (int nt = 0; nt < 2; nt++) {
        int n = n0 + nhalf + nt * 16 + mi;
        float v = acc[mt][nt][r] + bv;
        ps += v; pq += v * v;
        Yo[(size_t)m * NPTS + n] = f2bf(v);
      }
#pragma unroll
      for (int off = 1; off < 16; off <<= 1) {
        ps += __shfl_xor(ps, off, 16);
        pq += __shfl_xor(pq, off, 16);
      }
      if (mi == 0) {
        atomicAdd(&sb[m], ps);
        atomicAdd(&qb[m], pq);
      }
    }
  }
}

// ---------------- final BN+ReLU: read y1 bf16, write out fp32 ----------------
__global__ __launch_bounds__(256) void bn_apply_kernel(
    const unsigned short* __restrict__ y1, float* __restrict__ out,
    const float* __restrict__ stats, const float* __restrict__ gamma,
    const float* __restrict__ beta) {
  __shared__ float sh2[2];
  int idx0 = blockIdx.x * 1024;          // 1024 contiguous elems per block
  int c = (idx0 >> 13) & (H1 - 1);       // single channel per block (1024 | 8192)
  int t = threadIdx.x;
  if (t < 32) {
    float ms = stats[t * 768 + 512 + c];
    float vs = stats[t * 768 + 640 + c];
#pragma unroll
    for (int off = 16; off > 0; off >>= 1) {
      ms += __shfl_down(ms, off, 32);
      vs += __shfl_down(vs, off, 32);
    }
    if (t == 0) {
      const float inv = 1.f / (float)(BATCH * NPTS);
      float mean = ms * inv;
      float var = vs * inv - mean * mean;
      float ia = gamma[c] * rsqrtf(var + 1e-5f);
      sh2[0] = ia; sh2[1] = beta[c] - mean * ia;
    }
  }
  __syncthreads();
  float ia = sh2[0], sh = sh2[1];
  int i = idx0 + t * 4;
  ushort4 v = *(const ushort4*)(y1 + i);
  float4 o;
  o.x = fmaxf(fmaf(bf2f(v.x), ia, sh), 0.f);
  o.y = fmaxf(fmaf(bf2f(v.y), ia, sh), 0.f);
  o.z = fmaxf(fmaf(bf2f(v.z), ia, sh), 0.f);
  o.w = fmaxf(fmaf(bf2f(v.w), ia, sh), 0.f);
  *(float4*)(out + i) = o;
}

extern "C" void kernel_launch(void* const* d_in, const int* in_sizes, int n_in,
                              void* d_out, int out_size, void* d_ws, size_t ws_size,
                              hipStream_t stream) {
  const float* xyz1    = (const float*)d_in[0];
  const float* xyz2    = (const float*)d_in[1];
  const float* points1 = (const float*)d_in[2];
  const float* points2 = (const float*)d_in[3];
  const float* w0      = (const float*)d_in[4];
  const float* b0      = (const float*)d_in[5];
  const float* gamma0  = (const float*)d_in[6];
  const float* beta0   = (const float*)d_in[7];
  const float* w1      = (const float*)d_in[8];
  const float* b1      = (const float*)d_in[9];
  const float* gamma1  = (const float*)d_in[10];
  const float* beta1   = (const float*)d_in[11];
  float* out = (float*)d_out;

  char* ws = (char*)d_ws;
  unsigned short* p2tb = (unsigned short*)ws;  ws += (size_t)BATCH * SPTS * C2 * 2;   // 4.2 MB
  unsigned short* Xp = (unsigned short*)ws;    ws += (size_t)BATCH * NPTS * CIN * 2;  // 25.2 MB
  unsigned short* Y0 = (unsigned short*)ws;    ws += (size_t)BATCH * NPTS * H0 * 2;   // 16.8 MB ([b][n][o])
  unsigned short* y1 = (unsigned short*)ws;    ws += (size_t)BATCH * H1 * NPTS * 2;   // 8.4 MB ([b][m][n])
  unsigned short* Wp = (unsigned short*)ws;    ws += (size_t)(H0 * CIN + H1 * H0) * 2;
  float4* xyz2p = (float4*)(((uintptr_t)ws + 15) & ~(uintptr_t)15);
  ws = (char*)xyz2p + (size_t)BATCH * SPTS * 16;
  float* stats = (float*)ws;                   ws += (size_t)NSLICE * 768 * 4;  // 96 KB
  // per-slice layout: [0,256)=sum0, [256,512)=sq0, [512,640)=sum1, [640,768)=sq1
  (void)ws_size; (void)in_sizes; (void)n_in; (void)out_size;

  prep_kernel<<<dim3(1208), 256, 0, stream>>>(points2, p2tb, xyz2, xyz2p,
                                              w0, w1, Wp, points1, Xp, stats);
  knn_interp_kernel<<<dim3(NPTS / 64, BATCH), 1024, 0, stream>>>(xyz1, xyz2p, p2tb, Xp);
  gemm0_kernel<<<dim3(NPTS / 128, H0 / 128, BATCH), 256, 0, stream>>>(
      Wp, Xp, b0, Y0, stats);
  gemm1_kernel<<<dim3(NPTS / 64, 1, BATCH), 256, 0, stream>>>(
      Wp + H0 * CIN, Y0, b1, y1, stats, gamma0, beta0);
  bn_apply_kernel<<<dim3(BATCH * H1 * NPTS / 1024), 256, 0, stream>>>(
      y1, out, stats, gamma1, beta1);
}

// Round 12
// 176.179 us; speedup vs baseline: 2.1045x; 1.0037x over previous
//
#include <hip/hip_runtime.h>
#include <hip/hip_bf16.h>

#define BATCH 4
#define NPTS  8192
#define SPTS  2048
#define C1    128
#define C2    256
#define CIN   384   // C1+C2
#define H0    256
#define H1    128
#define NSLICE 32   // BN-stat accumulator slices

typedef __attribute__((ext_vector_type(8))) short bf16x8;
typedef __attribute__((ext_vector_type(4))) float f32x4;

__device__ __forceinline__ unsigned short f2bf(float x) {
  union { float f; unsigned u; } v; v.f = x;
  unsigned r = v.u + 0x7fff + ((v.u >> 16) & 1);   // RNE
  return (unsigned short)(r >> 16);
}
__device__ __forceinline__ float bf2f(unsigned short u) {
  union { unsigned u; float f; } v; v.u = ((unsigned)u) << 16; return v.f;
}

// ---------------- fused prep: all input-only packing in one launch ----------------
__global__ __launch_bounds__(256) void prep_kernel(
    const float* __restrict__ p2, unsigned short* __restrict__ p2tb,
    const float* __restrict__ xyz2, float4* __restrict__ xp,
    const float* __restrict__ w0, const float* __restrict__ w1,
    unsigned short* __restrict__ Wp,
    const float* __restrict__ p1, unsigned short* __restrict__ Xp,
    float* __restrict__ stats) {
  __shared__ unsigned short shmem[64 * 136];
  int bid = blockIdx.x;
  int t = threadIdx.x;

  if (bid < 512) {  // ---- transpose p2 -> bf16 ----
    int b = bid >> 7, rem = bid & 127;
    int s0 = (rem >> 2) * 64, c0 = (rem & 3) * 64;
    const float* src = p2 + (size_t)b * C2 * SPTS;
    int ss = t & 63, cseg = t >> 6;
#pragma unroll
    for (int i = 0; i < 16; i++) {
      int cc = cseg + i * 4;
      shmem[ss * 72 + cc] = f2bf(src[(size_t)(c0 + cc) * SPTS + s0 + ss]);
    }
    __syncthreads();
    int s = t >> 2, chunk = t & 3;
    uint4 v0 = *(const uint4*)&shmem[s * 72 + chunk * 16];
    uint4 v1 = *(const uint4*)&shmem[s * 72 + chunk * 16 + 8];
    unsigned short* dst = p2tb + (size_t)b * SPTS * C2 + (size_t)(s0 + s) * C2 + c0 + chunk * 16;
    *(uint4*)dst = v0;
    *(uint4*)(dst + 8) = v1;
  } else if (bid < 1024) {  // ---- pack p1 ----
    int b2 = bid - 512;
    int b = b2 >> 7, n0 = (b2 & 127) * 64;
    int nn = t & 63, c4 = t >> 6;
#pragma unroll
    for (int i = 0; i < 32; i++) {
      int c = i * 4 + c4;
      shmem[nn * 136 + c] = f2bf(p1[((size_t)b * C1 + c) * NPTS + n0 + nn]);
    }
    __syncthreads();
    int n = t >> 2;
#pragma unroll
    for (int j = 0; j < 4; j++) {
      int ch = (t & 3) + j * 4;
      uint4 v = *(const uint4*)&shmem[n * 136 + ch * 8];
      *(uint4*)&Xp[((size_t)b * NPTS + n0 + n) * CIN + ch * 8] = v;
    }
  } else if (bid < 1056) {  // ---- prepack xyz2 (pre-negated, doubled) ----
    int idx = (bid - 1024) * 256 + t;
    int b = idx >> 11, s = idx & (SPTS - 1);
    const float* x2 = xyz2 + (size_t)b * 3 * SPTS;
    float x = x2[s], y = x2[SPTS + s], z = x2[2 * SPTS + s];
    xp[idx] = make_float4(-2.f * x, -2.f * y, -2.f * z, x * x + y * y + z * z);
  } else if (bid < 1184) {  // ---- pack weights ----
    int idx = ((bid - 1056) * 256 + t) * 4;
    const float* src = (idx < H0 * CIN) ? (w0 + idx) : (w1 + (idx - H0 * CIN));
    float4 v = *(const float4*)src;
    ushort4 o;
    o.x = f2bf(v.x); o.y = f2bf(v.y); o.z = f2bf(v.z); o.w = f2bf(v.w);
    *(ushort4*)(Wp + idx) = o;
  } else {  // ---- zero BN stat accumulators ----
    int i4 = ((bid - 1184) * 256 + t) * 4;
    if (i4 < NSLICE * 768) *(float4*)(stats + i4) = make_float4(0.f, 0.f, 0.f, 0.f);
  }
}

// branchless top-3 insert: distances via fmin/fmed3, indices via cndmask (EXACT)
#define INS3(d, s, e0, e1, e2, j0, j1, j2)                        \
  {                                                               \
    bool lt0 = (d) < (e0), lt1 = (d) < (e1), lt2 = (d) < (e2);    \
    j2 = lt1 ? (j1) : (lt2 ? (s) : (j2));                         \
    j1 = lt0 ? (j0) : (lt1 ? (s) : (j1));                         \
    j0 = lt0 ? (s) : (j0);                                        \
    e2 = __builtin_amdgcn_fmed3f((d), (e1), (e2));                \
    e1 = __builtin_amdgcn_fmed3f((d), (e0), (e1));                \
    e0 = fminf((d), (e0));                                        \
  }

// ---------------- 3-NN search + fused interpolation ----------------
__global__ __launch_bounds__(1024) void knn_interp_kernel(
    const float* __restrict__ xyz1, const float4* __restrict__ xp,
    const unsigned short* __restrict__ p2tb, unsigned short* __restrict__ Xp) {
  int b = blockIdx.y;
  int t = threadIdx.x;
  int lane = t & 63;
  int w = __builtin_amdgcn_readfirstlane(t >> 6);  // 0..15
  int n = blockIdx.x * 64 + lane;
  const float* x1 = xyz1 + (size_t)b * 3 * NPTS;
  float px = x1[n], py = x1[NPTS + n], pz = x1[2 * NPTS + n];

  const int CHUNK = SPTS / 16;  // 128
  int sbase = w * CHUNK;
  const float4* cp = xp + (size_t)b * SPTS + sbase;

  float d0 = 3e38f, d1 = 3e38f, d2 = 3e38f;
  int i0 = 0, i1 = 0, i2 = 0;
#pragma unroll 8
  for (int j = 0; j < CHUNK; j++) {
    float4 c = cp[j];  // wave-uniform address -> scalar load
    float d = fmaf(c.z, pz, fmaf(c.y, py, fmaf(c.x, px, c.w)));
    int s = sbase + j;
    INS3(d, s, d0, d1, d2, i0, i1, i2);
  }

  __shared__ float dsh[16][64][3];
  __shared__ int   ish[16][64][3];
  __shared__ int   widx[64][3];
  __shared__ float wwgt[64][3];
  dsh[w][lane][0] = d0; dsh[w][lane][1] = d1; dsh[w][lane][2] = d2;
  ish[w][lane][0] = i0; ish[w][lane][1] = i1; ish[w][lane][2] = i2;
  __syncthreads();

  if (t < 256) {  // stage B: 4 groups merge 4 lists each
    int g = t >> 6, q = t & 63;
    float e0 = 3e38f, e1 = 3e38f, e2 = 3e38f;
    int j0 = 0, j1 = 0, j2 = 0;
#pragma unroll
    for (int c = 0; c < 4; c++) {
#pragma unroll
      for (int k = 0; k < 3; k++) {
        float d = dsh[4 * g + c][q][k];
        int s = ish[4 * g + c][q][k];
        INS3(d, s, e0, e1, e2, j0, j1, j2);
      }
    }
    dsh[4 * g][q][0] = e0; dsh[4 * g][q][1] = e1; dsh[4 * g][q][2] = e2;
    ish[4 * g][q][0] = j0; ish[4 * g][q][1] = j1; ish[4 * g][q][2] = j2;
  }
  __syncthreads();

  if (t < 64) {  // stage C: final merge; weights -> LDS
    float e0 = 3e38f, e1 = 3e38f, e2 = 3e38f;
    int j0 = 0, j1 = 0, j2 = 0;
#pragma unroll
    for (int c = 0; c < 4; c++) {
#pragma unroll
      for (int k = 0; k < 3; k++) {
        float d = dsh[4 * c][t][k];
        int s = ish[4 * c][t][k];
        INS3(d, s, e0, e1, e2, j0, j1, j2);
      }
    }
    float qq = fmaf(px, px, fmaf(py, py, pz * pz));
    float r0 = 1.f / (e0 + qq + 1e-8f);
    float r1 = 1.f / (e1 + qq + 1e-8f);
    float r2 = 1.f / (e2 + qq + 1e-8f);
    float rs = 1.f / (r0 + r1 + r2);
    widx[t][0] = j0; widx[t][1] = j1; widx[t][2] = j2;
    wwgt[t][0] = r0 * rs; wwgt[t][1] = r1 * rs; wwgt[t][2] = r2 * rs;
  }
  __syncthreads();

  // ---- fused interpolation ----
  const unsigned short* base = p2tb + (size_t)b * SPTS * C2;
  int c2 = (t & 127) * 2;
  int psub = t >> 7;
  unsigned short* xrow = Xp + ((size_t)b * NPTS + blockIdx.x * 64) * CIN + C1 + c2;
#pragma unroll
  for (int i = 0; i < 8; i++) {
    int pl = psub + i * 8;
    int g0 = widx[pl][0], g1 = widx[pl][1], g2 = widx[pl][2];
    float w0v = wwgt[pl][0], w1v = wwgt[pl][1], w2v = wwgt[pl][2];
    unsigned a0 = *(const unsigned*)(base + (size_t)g0 * C2 + c2);
    unsigned a1 = *(const unsigned*)(base + (size_t)g1 * C2 + c2);
    unsigned a2 = *(const unsigned*)(base + (size_t)g2 * C2 + c2);
    float v0 = w0v * bf2f((unsigned short)a0) + w1v * bf2f((unsigned short)a1) +
               w2v * bf2f((unsigned short)a2);
    float v1 = w0v * bf2f((unsigned short)(a0 >> 16)) + w1v * bf2f((unsigned short)(a1 >> 16)) +
               w2v * bf2f((unsigned short)(a2 >> 16));
    unsigned pk = (unsigned)f2bf(v0) | ((unsigned)f2bf(v1) << 16);
    *(unsigned*)(xrow + (size_t)pl * CIN) = pk;
  }
}

// LDS chunk swizzle: 16B chunk c of 64B row r lives at position c ^ ((r>>1)&3).
// Applied on global SOURCE (gload_lds writes linearly) + fragment-read offset
// (both-sides-or-neither). Spreads 16-lane quarter-wave reads over 8 bank-sets
// -> 2-way (free) instead of 8-way (2.94x).

// ---------------- GEMM0: 128x128 tiles, 512 blocks (2/CU), triple-buffered
// counted-vmcnt + swizzled LDS; epilogue: bias + sliced BN0 stats -> Y0 bf16.
__global__ __launch_bounds__(256) void gemm0_kernel(
    const unsigned short* __restrict__ A, const unsigned short* __restrict__ X,
    const float* __restrict__ bias, unsigned short* __restrict__ Y0,
    float* __restrict__ stats) {
  constexpr int KD = CIN;  // 384
  __shared__ unsigned short lds[24576];  // 48KB: As[3]@0, Bs[3]@12288; epilogue tile[128][136]
  int b = blockIdx.z;
  int n0 = blockIdx.x * 128;
  int o0 = blockIdx.y * 128;
  int t = threadIdx.x;
  int lane = t & 63;
  int w = __builtin_amdgcn_readfirstlane(t >> 6);
  int mhalf = (w & 1) * 64, nhalf = (w >> 1) * 64;
  const unsigned short* Xb = X + (size_t)b * NPTS * KD;
  int rA = lane >> 2;
  int c4 = lane >> 4;       // fragment k-chunk 0..3

  auto stage = [&](int buf, int k0) {
#pragma unroll
    for (int q = 0; q < 2; q++) {
      int r0 = w * 32 + q * 16;
      int row = r0 + rA;                                  // local tile row
      int csw = ((lane & 3) ^ ((row >> 1) & 3)) * 8;      // swizzled source chunk
      const unsigned short* ga = A + (size_t)(o0 + row) * KD + k0 + csw;
      __builtin_amdgcn_global_load_lds(
          (const __attribute__((address_space(1))) void*)ga,
          (__attribute__((address_space(3))) void*)(lds + buf * 4096 + r0 * 32), 16, 0, 0);
      const unsigned short* gb = Xb + (size_t)(n0 + row) * KD + k0 + csw;
      __builtin_amdgcn_global_load_lds(
          (const __attribute__((address_space(1))) void*)gb,
          (__attribute__((address_space(3))) void*)(lds + 12288 + buf * 4096 + r0 * 32), 16, 0, 0);
    }
  };

  constexpr int NT = KD / 32;  // 12
  f32x4 acc[4][4] = {};
  int mi = lane & 15;

  stage(0, 0);
  stage(1, 32);

#pragma unroll
  for (int kt = 0; kt < NT; ++kt) {
    if (kt < NT - 1) asm volatile("s_waitcnt vmcnt(4)" ::: "memory");
    else             asm volatile("s_waitcnt vmcnt(0)" ::: "memory");
    __builtin_amdgcn_s_barrier();
    asm volatile("" ::: "memory");
    __builtin_amdgcn_sched_barrier(0);

    if (kt + 2 < NT) stage((kt + 2) % 3, (kt + 2) * 32);

    const unsigned short* Ac = lds + (kt % 3) * 4096;
    const unsigned short* Bc = lds + 12288 + (kt % 3) * 4096;
    bf16x8 af[4], bfr[4];
#pragma unroll
    for (int i = 0; i < 4; i++) {
      int ra = mhalf + i * 16 + mi;
      int rb = nhalf + i * 16 + mi;
      af[i]  = *(const bf16x8*)(Ac + ra * 32 + ((c4 ^ ((ra >> 1) & 3)) << 3));
      bfr[i] = *(const bf16x8*)(Bc + rb * 32 + ((c4 ^ ((rb >> 1) & 3)) << 3));
    }
#pragma unroll
    for (int mt = 0; mt < 4; mt++)
#pragma unroll
      for (int nt = 0; nt < 4; nt++)
        acc[mt][nt] = __builtin_amdgcn_mfma_f32_16x16x32_bf16(
            af[mt], bfr[nt], acc[mt][nt], 0, 0, 0);
  }

  __syncthreads();  // all MFMA consumed LDS; safe to reuse as transpose tile

  int slice = ((blockIdx.x << 2) + blockIdx.z) & (NSLICE - 1);
  float* sb = stats + slice * 768;        // sum0
  float* qb = stats + slice * 768 + 256;  // sq0

  int rq = (lane >> 4) * 4;
#pragma unroll
  for (int mt = 0; mt < 4; mt++) {
#pragma unroll
    for (int r = 0; r < 4; r++) {
      int ml = mhalf + mt * 16 + rq + r;
      float bv = bias[o0 + ml];
      float ps = 0.f, pq = 0.f;
#pragma unroll
      for (int nt = 0; nt < 4; nt++) {
        int nl = nhalf + nt * 16 + mi;
        float v = acc[mt][nt][r] + bv;
        ps += v; pq += v * v;
        lds[nl * 136 + ml] = f2bf(v);   // [n_local][m_local] transpose tile
      }
#pragma unroll
      for (int off = 1; off < 16; off <<= 1) {
        ps += __shfl_xor(ps, off, 16);
        pq += __shfl_xor(pq, off, 16);
      }
      if (mi == 0) {
        atomicAdd(&sb[o0 + ml], ps);
        atomicAdd(&qb[o0 + ml], pq);
      }
    }
  }
  __syncthreads();

  // coalesced store: Y0[b][n0+row][o0 .. o0+127]
  int row = t >> 1, ch0 = (t & 1) * 64;
  unsigned short* Yr = Y0 + ((size_t)b * NPTS + n0 + row) * H0 + o0 + ch0;
#pragma unroll
  for (int j = 0; j < 8; j++) {
    uint4 v = *(const uint4*)&lds[row * 136 + ch0 + j * 8];
    *(uint4*)(Yr + j * 8) = v;
  }
}

// ---------------- GEMM1: 64-wide n-tiles (512 blocks, 2/CU); B reg-staged with
// fused BN0+ReLU; 2-deep counted-vmcnt pipeline; swizzled LDS (As src-side,
// Bs write-side); fused BN1 stats; y1 bf16 out.
__global__ __launch_bounds__(256) void gemm1_kernel(
    const unsigned short* __restrict__ A, const unsigned short* __restrict__ Y0,
    const float* __restrict__ bias, unsigned short* __restrict__ y1,
    float* __restrict__ stats, const float* __restrict__ gamma0,
    const float* __restrict__ beta0) {
  constexpr int KD = H0;  // 256
  __shared__ unsigned short As[3][4096];   // 128 x 32 x3
  __shared__ unsigned short Bs[2][2048];   // 64 x 32 x2
  __shared__ float aS[256], sS[256];
  int b = blockIdx.z;
  int n0 = blockIdx.x * 64;
  int t = threadIdx.x;
  int lane = t & 63;
  int w = __builtin_amdgcn_readfirstlane(t >> 6);
  int mhalf = (w & 1) * 64;       // m: 2 x 64
  int nhalf = (w >> 1) * 32;      // n: 2 x 32
  int rA = lane >> 2;
  int cofs = (lane & 3) * 8;
  int c4 = lane >> 4;
  const unsigned short* Yb = Y0 + ((size_t)b * NPTS + n0) * KD;

  // BN0 coefficients from 32-slice stats (channel = t)
  {
    float ms = 0.f, vs = 0.f;
#pragma unroll 8
    for (int sl = 0; sl < NSLICE; sl++) {
      ms += stats[sl * 768 + t];
      vs += stats[sl * 768 + 256 + t];
    }
    const float inv = 1.f / (float)(BATCH * NPTS);
    float mean = ms * inv;
    float var = vs * inv - mean * mean;
    float ia = gamma0[t] * rsqrtf(var + 1e-5f);
    aS[t] = ia; sS[t] = beta0[t] - mean * ia;
  }
  __syncthreads();

  auto stageA = [&](int buf, int k0) {   // 2 VMEM ops; swizzled source
#pragma unroll
    for (int q = 0; q < 2; q++) {
      int r0 = w * 32 + q * 16;
      int row = r0 + rA;
      int csw = ((lane & 3) ^ ((row >> 1) & 3)) * 8;
      const unsigned short* ga = A + (size_t)row * KD + k0 + csw;
      __builtin_amdgcn_global_load_lds(
          (const __attribute__((address_space(1))) void*)ga,
          (__attribute__((address_space(3))) void*)(&As[buf][r0 * 32]), 16, 0, 0);
    }
  };
  bf16x8 br[2];
  auto loadB = [&](int slot, int k0) {   // 1 VMEM op (unswizzled global read)
    br[slot] = *(const bf16x8*)(Yb + (size_t)(w * 16 + rA) * KD + k0 + cofs);
  };
  auto writeB = [&](int buf, int slot, int k0) {  // swizzled ds_write position
    int row = w * 16 + rA;
    int psw = ((lane & 3) ^ ((row >> 1) & 3)) * 8;
    bf16x8 v = br[slot], o;
#pragma unroll
    for (int e = 0; e < 8; e++) {
      float f = bf2f((unsigned short)v[e]);
      f = fmaxf(fmaf(f, aS[k0 + cofs + e], sS[k0 + cofs + e]), 0.f);
      o[e] = (short)f2bf(f);
    }
    *(bf16x8*)(&Bs[buf][row * 32 + psw]) = o;
  };

  constexpr int NT = KD / 32;  // 8
  f32x4 acc[4][2] = {};
  int mi = lane & 15;

  // prologue: steps 0 and 1 in flight (6 VMEM ops)
  stageA(0, 0);      loadB(0, 0);
  stageA(1, 32);     loadB(1, 32);

#pragma unroll
  for (int kt = 0; kt < NT; ++kt) {
    // oldest step's 3 ops landed; newest step (kt+1) stays in flight
    if (kt < NT - 1) asm volatile("s_waitcnt vmcnt(3)" ::: "memory");
    else             asm volatile("s_waitcnt vmcnt(0)" ::: "memory");
    __builtin_amdgcn_sched_barrier(0);
    writeB(kt & 1, kt & 1, kt * 32);       // BN0+ReLU transform -> Bs[kt&1]
    asm volatile("s_waitcnt lgkmcnt(0)" ::: "memory");
    asm volatile("s_barrier" ::: "memory");
    __builtin_amdgcn_sched_barrier(0);
    // issue step kt+2 (As slot (kt+2)%3 free; br slot kt&1 consumed above)
    if (kt + 2 < NT) { stageA((kt + 2) % 3, (kt + 2) * 32); loadB(kt & 1, (kt + 2) * 32); }

    bf16x8 af[4], bfr[2];
#pragma unroll
    for (int i = 0; i < 4; i++) {
      int ra = mhalf + i * 16 + mi;
      af[i] = *(const bf16x8*)(&As[kt % 3][ra * 32 + ((c4 ^ ((ra >> 1) & 3)) << 3)]);
    }
#pragma unroll
    for (int j = 0; j < 2; j++) {
      int rb = nhalf + j * 16 + mi;
      bfr[j] = *(const bf16x8*)(&Bs[kt & 1][rb * 32 + ((c4 ^ ((rb >> 1) & 3)) << 3)]);
    }
#pragma unroll
    for (int mt = 0; mt < 4; mt++)
#pragma unroll
      for (int nt = 0; nt < 2; nt++)
        acc[mt][nt] = __builtin_amdgcn_mfma_f32_16x16x32_bf16(
            af[mt], bfr[nt], acc[mt][nt], 0, 0, 0);
  }

  int slice = ((blockIdx.x << 2) + blockIdx.z) & (NSLICE - 1);
  float* sb = stats + slice * 768 + 512;  // sum1
  float* qb = stats + slice * 768 + 640;  // sq1
  unsigned short* Yo = y1 + (size_t)b * H1 * NPTS;

  int rq = (lane >> 4) * 4;
#pragma unroll
  for (int mt = 0; mt < 4; mt++) {
#pragma unroll
    for (int r = 0; r < 4; r++) {
      int m = mhalf + mt * 16 + rq + r;
      float bv = bias[m];
      float ps = 0.f, pq = 0.f;
#pragma unroll
      for (int nt = 0; nt < 2; nt++) {
        int n = n0 + nhalf + nt * 16 + mi;
        float v = acc[mt][nt][r] + bv;
        ps += v; pq += v * v;
        Yo[(size_t)m * NPTS + n] = f2bf(v);
      }
#pragma unroll
      for (int off = 1; off < 16; off <<= 1) {
        ps += __shfl_xor(ps, off, 16);
        pq += __shfl_xor(pq, off, 16);
      }
      if (mi == 0) {
        atomicAdd(&sb[m], ps);
        atomicAdd(&qb[m], pq);
      }
    }
  }
}

// ---------------- final BN+ReLU: read y1 bf16, write out fp32 ----------------
__global__ __launch_bounds__(256) void bn_apply_kernel(
    const unsigned short* __restrict__ y1, float* __restrict__ out,
    const float* __restrict__ stats, const float* __restrict__ gamma,
    const float* __restrict__ beta) {
  __shared__ float sh2[2];
  int idx0 = blockIdx.x * 1024;          // 1024 contiguous elems per block
  int c = (idx0 >> 13) & (H1 - 1);       // single channel per block (1024 | 8192)
  int t = threadIdx.x;
  if (t < 32) {
    float ms = stats[t * 768 + 512 + c];
    float vs = stats[t * 768 + 640 + c];
#pragma unroll
    for (int off = 16; off > 0; off >>= 1) {
      ms += __shfl_down(ms, off, 32);
      vs += __shfl_down(vs, off, 32);
    }
    if (t == 0) {
      const float inv = 1.f / (float)(BATCH * NPTS);
      float mean = ms * inv;
      float var = vs * inv - mean * mean;
      float ia = gamma[c] * rsqrtf(var + 1e-5f);
      sh2[0] = ia; sh2[1] = beta[c] - mean * ia;
    }
  }
  __syncthreads();
  float ia = sh2[0], sh = sh2[1];
  int i = idx0 + t * 4;
  ushort4 v = *(const ushort4*)(y1 + i);
  float4 o;
  o.x = fmaxf(fmaf(bf2f(v.x), ia, sh), 0.f);
  o.y = fmaxf(fmaf(bf2f(v.y), ia, sh), 0.f);
  o.z = fmaxf(fmaf(bf2f(v.z), ia, sh), 0.f);
  o.w = fmaxf(fmaf(bf2f(v.w), ia, sh), 0.f);
  *(float4*)(out + i) = o;
}

extern "C" void kernel_launch(void* const* d_in, const int* in_sizes, int n_in,
                              void* d_out, int out_size, void* d_ws, size_t ws_size,
                              hipStream_t stream) {
  const float* xyz1    = (const float*)d_in[0];
  const float* xyz2    = (const float*)d_in[1];
  const float* points1 = (const float*)d_in[2];
  const float* points2 = (const float*)d_in[3];
  const float* w0      = (const float*)d_in[4];
  const float* b0      = (const float*)d_in[5];
  const float* gamma0  = (const float*)d_in[6];
  const float* beta0   = (const float*)d_in[7];
  const float* w1      = (const float*)d_in[8];
  const float* b1      = (const float*)d_in[9];
  const float* gamma1  = (const float*)d_in[10];
  const float* beta1   = (const float*)d_in[11];
  float* out = (float*)d_out;

  char* ws = (char*)d_ws;
  unsigned short* p2tb = (unsigned short*)ws;  ws += (size_t)BATCH * SPTS * C2 * 2;   // 4.2 MB
  unsigned short* Xp = (unsigned short*)ws;    ws += (size_t)BATCH * NPTS * CIN * 2;  // 25.2 MB
  unsigned short* Y0 = (unsigned short*)ws;    ws += (size_t)BATCH * NPTS * H0 * 2;   // 16.8 MB ([b][n][o])
  unsigned short* y1 = (unsigned short*)ws;    ws += (size_t)BATCH * H1 * NPTS * 2;   // 8.4 MB ([b][m][n])
  unsigned short* Wp = (unsigned short*)ws;    ws += (size_t)(H0 * CIN + H1 * H0) * 2;
  float4* xyz2p = (float4*)(((uintptr_t)ws + 15) & ~(uintptr_t)15);
  ws = (char*)xyz2p + (size_t)BATCH * SPTS * 16;
  float* stats = (float*)ws;                   ws += (size_t)NSLICE * 768 * 4;  // 96 KB
  // per-slice layout: [0,256)=sum0, [256,512)=sq0, [512,640)=sum1, [640,768)=sq1
  (void)ws_size; (void)in_sizes; (void)n_in; (void)out_size;

  prep_kernel<<<dim3(1208), 256, 0, stream>>>(points2, p2tb, xyz2, xyz2p,
                                              w0, w1, Wp, points1, Xp, stats);
  knn_interp_kernel<<<dim3(NPTS / 64, BATCH), 1024, 0, stream>>>(xyz1, xyz2p, p2tb, Xp);
  gemm0_kernel<<<dim3(NPTS / 128, H0 / 128, BATCH), 256, 0, stream>>>(
      Wp, Xp, b0, Y0, stats);
  gemm1_kernel<<<dim3(NPTS / 64, 1, BATCH), 256, 0, stream>>>(
      Wp + H0 * CIN, Y0, b1, y1, stats, gamma0, beta0);
  bn_apply_kernel<<<dim3(BATCH * H1 * NPTS / 1024), 256, 0, stream>>>(
      y1, out, stats, gamma1, beta1);
}